// Round 1
// baseline (4470.962 us; speedup 1.0000x reference)
//
#include <hip/hip_runtime.h>
#include <hip/hip_bf16.h>
#include <math.h>

// Problem constants
#define B_   32
#define L_   1024
#define H_   12
#define DV   64
#define MH   64
#define MM   128      // M = 2*Mh
#define HD   768      // hdim
#define BH_  384      // B*H

typedef unsigned int  uint32;
typedef unsigned short ushort16;

__device__ __forceinline__ float bf2f(uint32 u) {
  return __uint_as_float(u << 16);
}
__device__ __forceinline__ ushort16 f2bf(float f) {
  uint32 x = __float_as_uint(f);
  x += 0x7FFFu + ((x >> 16) & 1u);   // RNE
  return (ushort16)(x >> 16);
}
__device__ __forceinline__ uint32 pack2bf(float a, float b) {
  return (uint32)f2bf(a) | ((uint32)f2bf(b) << 16);
}

// ---------------------------------------------------------------------------
// K0: omega_scaled (transposed to [h][m][d]) + zero kl accumulators
// ---------------------------------------------------------------------------
__global__ void k0_prep(const float* __restrict__ omega_half,
                        const float* __restrict__ log_ls,
                        float* __restrict__ omT,
                        float* __restrict__ klbuf) {
  int h = blockIdx.x;
  for (int e = threadIdx.x; e < MH * DV; e += blockDim.x) {
    int m = e >> 6, d = e & 63;
    float scale = 1.41421356237f * expf(-log_ls[h * DV + d]);
    omT[h * MH * DV + m * DV + d] = omega_half[h * DV * MH + d * MH + m] * scale;
  }
  if (blockIdx.x == 0) {
    for (int e = threadIdx.x; e < BH_; e += blockDim.x) klbuf[e] = 0.f;
  }
}

// ---------------------------------------------------------------------------
// K1: qv = x @ W_qv^T  (32768x1536x768 fp32), output bf16 permuted to
//     layout [b][h][l][c] with c in [0,128): c<64 = q, c>=64 = v.
//     128x128 tile, K-tile 16, 256 threads, 8x8 acc per thread.
// ---------------------------------------------------------------------------
__global__ __launch_bounds__(256)
void k1_qv(const float* __restrict__ x, const float* __restrict__ Wqv,
           ushort16* __restrict__ qv) {
  __shared__ float As[16][128];
  __shared__ float Bs[16][128];
  int tid = threadIdx.x;
  int tm = blockIdx.x / H_;
  int h  = blockIdx.x % H_;     // col tile == head (128 cols per head)
  int m0 = tm * 128;
  int n0 = h * 128;
  int ty = tid >> 4, tx = tid & 15;
  float acc[8][8];
#pragma unroll
  for (int i = 0; i < 8; i++)
#pragma unroll
    for (int j = 0; j < 8; j++) acc[i][j] = 0.f;

  for (int k0 = 0; k0 < HD; k0 += 16) {
    __syncthreads();
#pragma unroll
    for (int q = 0; q < 2; q++) {
      int i = tid * 2 + q;
      int row = i >> 2, kq = i & 3;
      float4 av = *(const float4*)&x[(size_t)(m0 + row) * HD + k0 + kq * 4];
      As[kq * 4 + 0][row] = av.x; As[kq * 4 + 1][row] = av.y;
      As[kq * 4 + 2][row] = av.z; As[kq * 4 + 3][row] = av.w;
      float4 bv = *(const float4*)&Wqv[(size_t)(n0 + row) * HD + k0 + kq * 4];
      Bs[kq * 4 + 0][row] = bv.x; Bs[kq * 4 + 1][row] = bv.y;
      Bs[kq * 4 + 2][row] = bv.z; Bs[kq * 4 + 3][row] = bv.w;
    }
    __syncthreads();
#pragma unroll
    for (int k = 0; k < 16; k++) {
      float a[8], b[8];
      *(float4*)&a[0] = *(float4*)&As[k][ty * 8];
      *(float4*)&a[4] = *(float4*)&As[k][ty * 8 + 4];
      *(float4*)&b[0] = *(float4*)&Bs[k][tx * 8];
      *(float4*)&b[4] = *(float4*)&Bs[k][tx * 8 + 4];
#pragma unroll
      for (int i = 0; i < 8; i++)
#pragma unroll
        for (int j = 0; j < 8; j++) acc[i][j] = fmaf(a[i], b[j], acc[i][j]);
    }
  }
#pragma unroll
  for (int i = 0; i < 8; i++) {
    int n = m0 + ty * 8 + i;
    int b = n >> 10, l = n & 1023;
    size_t base = (((size_t)(b * H_ + h) * L_) + l) * MM + tx * 8;
    uint4 w;
    w.x = pack2bf(acc[i][0], acc[i][1]);
    w.y = pack2bf(acc[i][2], acc[i][3]);
    w.z = pack2bf(acc[i][4], acc[i][5]);
    w.w = pack2bf(acc[i][6], acc[i][7]);
    *(uint4*)&qv[base] = w;
  }
}

// ---------------------------------------------------------------------------
// K2: per (b,h): G = phi^T phi (128x128), C = phi^T v (128x64).
//     phi recomputed from q; chunk 32 rows; 256 threads; reg-tiled 8x8 / 8x4.
// ---------------------------------------------------------------------------
__global__ __launch_bounds__(256)
void k2_gram(const ushort16* __restrict__ qv, const float* __restrict__ omT,
             const float* __restrict__ phase, const float* __restrict__ log_sf,
             float* __restrict__ Gws, float* __restrict__ Cws) {
  __shared__ float OmS[MH][DV];     // [m][d]
  __shared__ float qS[32][DV];
  __shared__ float vS[32][DV];
  __shared__ float phS[32][MM];
  __shared__ float phaseS[MH];
  int bh = blockIdx.x;
  int h = bh % H_;
  int tid = threadIdx.x;
  for (int e = tid; e < MH * DV; e += 256) OmS[e >> 6][e & 63] = omT[h * MH * DV + e];
  if (tid < MH) phaseS[tid] = phase[h * MH + tid];
  float amp = sqrtf(expf(log_sf[h])) * 0.08838834764831845f;  // 1/sqrt(128)
  int ty = tid >> 4, tx = tid & 15;
  float gacc[8][8];
  float cacc[8][4];
#pragma unroll
  for (int i = 0; i < 8; i++) {
#pragma unroll
    for (int j = 0; j < 8; j++) gacc[i][j] = 0.f;
#pragma unroll
    for (int j = 0; j < 4; j++) cacc[i][j] = 0.f;
  }
  const ushort16* qp = qv + (size_t)bh * L_ * MM;

  for (int l0 = 0; l0 < L_; l0 += 32) {
    __syncthreads();
#pragma unroll
    for (int q = 0; q < 2; q++) {
      int i = tid + q * 256;           // 0..511
      int row = i >> 4, g = i & 15;
      uint4 w = *(const uint4*)&qp[(size_t)(l0 + row) * MM + g * 8];
      float f0 = bf2f(w.x & 0xffffu), f1 = bf2f(w.x >> 16);
      float f2 = bf2f(w.y & 0xffffu), f3 = bf2f(w.y >> 16);
      float f4 = bf2f(w.z & 0xffffu), f5 = bf2f(w.z >> 16);
      float f6 = bf2f(w.w & 0xffffu), f7 = bf2f(w.w >> 16);
      float* dst = (g < 8) ? &qS[row][g * 8] : &vS[row][(g - 8) * 8];
      dst[0] = f0; dst[1] = f1; dst[2] = f2; dst[3] = f3;
      dst[4] = f4; dst[5] = f5; dst[6] = f6; dst[7] = f7;
    }
    __syncthreads();
    for (int p = tid; p < 32 * MH; p += 256) {
      int r = p >> 6, m = p & 63;
      float s = phaseS[m];
#pragma unroll
      for (int d = 0; d < DV; d += 4) {
        float4 qq = *(float4*)&qS[r][d];
        float4 oo = *(float4*)&OmS[m][d];
        s = fmaf(qq.x, oo.x, s); s = fmaf(qq.y, oo.y, s);
        s = fmaf(qq.z, oo.z, s); s = fmaf(qq.w, oo.w, s);
      }
      float sv, cv;
      sincosf(s, &sv, &cv);
      phS[r][m]      = amp * cv;
      phS[r][MH + m] = amp * sv;
    }
    __syncthreads();
    for (int r = 0; r < 32; r++) {
      float a[8], b[8], vv[4];
      *(float4*)&a[0] = *(float4*)&phS[r][ty * 8];
      *(float4*)&a[4] = *(float4*)&phS[r][ty * 8 + 4];
      *(float4*)&b[0] = *(float4*)&phS[r][tx * 8];
      *(float4*)&b[4] = *(float4*)&phS[r][tx * 8 + 4];
      *(float4*)&vv[0] = *(float4*)&vS[r][tx * 4];
#pragma unroll
      for (int i = 0; i < 8; i++) {
#pragma unroll
        for (int j = 0; j < 8; j++) gacc[i][j] = fmaf(a[i], b[j], gacc[i][j]);
#pragma unroll
        for (int j = 0; j < 4; j++) cacc[i][j] = fmaf(a[i], vv[j], cacc[i][j]);
      }
    }
  }
  float* Gp = Gws + (size_t)bh * MM * MM;
#pragma unroll
  for (int i = 0; i < 8; i++) {
    int row = ty * 8 + i;
    *(float4*)&Gp[row * MM + tx * 8]     = make_float4(gacc[i][0], gacc[i][1], gacc[i][2], gacc[i][3]);
    *(float4*)&Gp[row * MM + tx * 8 + 4] = make_float4(gacc[i][4], gacc[i][5], gacc[i][6], gacc[i][7]);
  }
  float* Cp = Cws + (size_t)bh * MM * DV;
#pragma unroll
  for (int i = 0; i < 8; i++) {
    int row = ty * 8 + i;
    *(float4*)&Cp[row * DV + tx * 4] = make_float4(cacc[i][0], cacc[i][1], cacc[i][2], cacc[i][3]);
  }
}

// ---------------------------------------------------------------------------
// K3: per (b,h): A = G + (sigma2+1e-6) I; Cholesky (diag kept SQUARED to
//     avoid RMW races); Linv into upper triangle (skewed layout -> LDS column
//     access is bank-conflict-free); Ainv = Linv^T Linv -> global (over G);
//     KL pieces accumulated via one atomicAdd per thread.
// ---------------------------------------------------------------------------
#define LB_(i,k) LBs[((i) << 7) + (((k) + (i)) & 127)]

__global__ __launch_bounds__(256)
void k3_factor(const float* __restrict__ Gws, const float* __restrict__ Cws,
               const float* __restrict__ log_sigma2,
               float* __restrict__ Ainvws, float* __restrict__ klbuf) {
  __shared__ float LBs[MM * MM];     // 64 KB exactly
  int bh = blockIdx.x;
  int tid = threadIdx.x;
  float ls = log_sigma2[0];
  float sigma2 = expf(ls);
  float cjit = sigma2 + 1e-6f;
  const float* Gp = Gws + (size_t)bh * MM * MM;
  for (int e = tid; e < MM * MM; e += 256) {
    int m = e >> 7, n = e & 127;
    float g = Gp[e];
    if (m == n) g += cjit;
    LB_(m, n) = g;
  }
  float klp = 0.f;

  // Cholesky (lower). Diagonal entries stay as L[j][j]^2 (never overwritten).
  for (int j = 0; j < MM; j++) {
    __syncthreads();
    float djj = LB_(j, j);
    float rinv = 1.f / sqrtf(djj);
    for (int i = j + 1 + tid; i < MM; i += 256) LB_(i, j) *= rinv;
    __syncthreads();
    int k = j + 1 + tid;
    if (k < MM) {
      float ck = LB_(k, j);
      for (int i = k; i < MM; i++) LB_(i, k) -= ck * LB_(i, j);
    }
  }
  __syncthreads();

  // Linv: column c by thread c; Linv[i][c] stored at logical upper (c,i).
  if (tid < MM) {
    int c = tid;
    float diagc = LB_(c, c);             // = L[c][c]^2
    klp += 32.f * logf(diagc);           // 0.5*Dv*logdetA share: 64*log(Lcc)
    float xc = 1.f / sqrtf(diagc);
    for (int i = c + 1; i < MM; i++) {
      float ssum = LB_(i, c) * xc;
      for (int k = c + 1; k < i; k++) ssum += LB_(i, k) * LB_(c, k);
      LB_(c, i) = -ssum / sqrtf(LB_(i, i));
    }
  }
  __syncthreads();

  // Ainv = Linv^T Linv -> global (aliases G buffer; G fully consumed above)
  float* Ap = Ainvws + (size_t)bh * MM * MM;
  for (int t = 0; t < 64; t++) {
    int e = tid + t * 256;
    int m = e >> 7, n = e & 127;
    int mx = m > n ? m : n;
    float invm = 1.f / sqrtf(LB_(m, m));
    float invn = 1.f / sqrtf(LB_(n, n));
    float s = 0.f;
    for (int i = mx; i < MM; i++) {
      float lm = (i == m) ? invm : LB_(m, i);
      float ln = (i == n) ? invn : LB_(n, i);
      s = fmaf(lm, ln, s);
    }
    Ap[e] = s;
    if (m == n) klp += 32.f * sigma2 * s;   // 0.5*Dv*sigma2*tr(Ainv)
  }
  __syncthreads();   // makes this block's Ainv global writes visible

  // mu_norm2 = ||Ainv C||_F^2 (W2 not stored)
  const float* Cp = Cws + (size_t)bh * MM * DV;
  for (int t = 0; t < 32; t++) {
    int e = tid + t * 256;
    int m = e >> 6, d = e & 63;
    const float* Arow = &Ap[m * MM];
    float s = 0.f;
    for (int n = 0; n < MM; n++) s = fmaf(Arow[n], Cp[n * DV + d], s);
    klp += 0.5f * s * s;
  }
  if (tid == 0) klp += -4096.f - 4096.f * ls;   // 0.5*(-k - Dv*M*log(sigma2))
  atomicAdd(&klbuf[bh], klp);
}

// ---------------------------------------------------------------------------
// K4: per (b,h): for each row l: recompute phi; t = Ainv*phi;
//     var = sigma2*phi.t; mean = t.C; sfeat = mean + sqrt(var)*eps (bf16).
//     Chunk = 8 rows; wave-halves: 32 lanes per row (4 n's / 2 d's per lane).
// ---------------------------------------------------------------------------
__global__ __launch_bounds__(256)
void k4_sample(const ushort16* __restrict__ qv, const float* __restrict__ omT,
               const float* __restrict__ phase, const float* __restrict__ log_sf,
               const float* __restrict__ log_sigma2,
               const float* __restrict__ Ainvws, const float* __restrict__ Cws,
               const float* __restrict__ eps, ushort16* __restrict__ sfeat) {
  __shared__ ushort16 AinvS[MM * MM];      // 32768 B, bf16
  __shared__ ushort16 CST[DV * 132];       // 16896 B, bf16, [d][n] stride 132
  __shared__ ushort16 OmS[MH * DV];        // 8192 B, bf16, [m][d]
  __shared__ float    phS[8][MM];          // 4096 B
  __shared__ ushort16 tS[8][MM];           // 2048 B, bf16
  __shared__ float    phaseS[MH];          // 256 B  -> total 64256 B
  int bh = blockIdx.x;
  int h = bh % H_;
  int b = bh / H_;
  int tid = threadIdx.x;
  const float* Ap = Ainvws + (size_t)bh * MM * MM;
  for (int e = tid; e < MM * MM; e += 256) AinvS[e] = f2bf(Ap[e]);
  const float* Cp = Cws + (size_t)bh * MM * DV;
  for (int e = tid; e < MM * DV; e += 256) {
    int d = e >> 7, n = e & 127;
    CST[d * 132 + n] = f2bf(Cp[n * DV + d]);
  }
  for (int e = tid; e < MH * DV; e += 256) OmS[e] = f2bf(omT[h * MH * DV + e]);
  if (tid < MH) phaseS[tid] = phase[h * MH + tid];
  float amp = sqrtf(expf(log_sf[h])) * 0.08838834764831845f;
  float sigma2 = expf(log_sigma2[0]);
  const ushort16* qp = qv + (size_t)bh * L_ * MM;
  const float* ep = eps + (size_t)bh * L_ * DV;
  ushort16* sp = sfeat + ((size_t)b * L_ * HD + h * DV);
  int lane = tid & 63;
  int half = lane & 31;
  int r = tid >> 5;          // row-in-chunk, 0..7 (one 32-lane half per row)
  int n0 = half * 4;
  int d0 = half * 2;

  for (int l0 = 0; l0 < L_; l0 += 8) {
    __syncthreads();
    // phi for 8 rows (512 proj values, 2 per thread)
#pragma unroll
    for (int q = 0; q < 2; q++) {
      int p = tid + q * 256;
      int rr = p >> 6, m = p & 63;
      const ushort16* qrow = &qp[(size_t)(l0 + rr) * MM];
      float s = phaseS[m];
#pragma unroll
      for (int d = 0; d < DV; d += 8) {
        uint4 qw = *(const uint4*)&qrow[d];
        uint4 ow = *(const uint4*)&OmS[m * DV + d];
        s = fmaf(bf2f(qw.x & 0xffffu), bf2f(ow.x & 0xffffu), s);
        s = fmaf(bf2f(qw.x >> 16),     bf2f(ow.x >> 16),     s);
        s = fmaf(bf2f(qw.y & 0xffffu), bf2f(ow.y & 0xffffu), s);
        s = fmaf(bf2f(qw.y >> 16),     bf2f(ow.y >> 16),     s);
        s = fmaf(bf2f(qw.z & 0xffffu), bf2f(ow.z & 0xffffu), s);
        s = fmaf(bf2f(qw.z >> 16),     bf2f(ow.z >> 16),     s);
        s = fmaf(bf2f(qw.w & 0xffffu), bf2f(ow.w & 0xffffu), s);
        s = fmaf(bf2f(qw.w >> 16),     bf2f(ow.w >> 16),     s);
      }
      float sv, cv;
      sincosf(s, &sv, &cv);
      phS[rr][m]      = amp * cv;
      phS[rr][MH + m] = amp * sv;
    }
    __syncthreads();
    // t = Ainv * phi (4 n's per lane)
    float4 acc = make_float4(0.f, 0.f, 0.f, 0.f);
    for (int m = 0; m < MM; m += 4) {
      float4 ph = *(float4*)&phS[r][m];
      uint2 a0 = *(uint2*)&AinvS[(m + 0) * MM + n0];
      uint2 a1 = *(uint2*)&AinvS[(m + 1) * MM + n0];
      uint2 a2 = *(uint2*)&AinvS[(m + 2) * MM + n0];
      uint2 a3 = *(uint2*)&AinvS[(m + 3) * MM + n0];
      acc.x = fmaf(ph.x, bf2f(a0.x & 0xffffu), acc.x);
      acc.y = fmaf(ph.x, bf2f(a0.x >> 16),     acc.y);
      acc.z = fmaf(ph.x, bf2f(a0.y & 0xffffu), acc.z);
      acc.w = fmaf(ph.x, bf2f(a0.y >> 16),     acc.w);
      acc.x = fmaf(ph.y, bf2f(a1.x & 0xffffu), acc.x);
      acc.y = fmaf(ph.y, bf2f(a1.x >> 16),     acc.y);
      acc.z = fmaf(ph.y, bf2f(a1.y & 0xffffu), acc.z);
      acc.w = fmaf(ph.y, bf2f(a1.y >> 16),     acc.w);
      acc.x = fmaf(ph.z, bf2f(a2.x & 0xffffu), acc.x);
      acc.y = fmaf(ph.z, bf2f(a2.x >> 16),     acc.y);
      acc.z = fmaf(ph.z, bf2f(a2.y & 0xffffu), acc.z);
      acc.w = fmaf(ph.z, bf2f(a2.y >> 16),     acc.w);
      acc.x = fmaf(ph.w, bf2f(a3.x & 0xffffu), acc.x);
      acc.y = fmaf(ph.w, bf2f(a3.x >> 16),     acc.y);
      acc.z = fmaf(ph.w, bf2f(a3.y & 0xffffu), acc.z);
      acc.w = fmaf(ph.w, bf2f(a3.y >> 16),     acc.w);
    }
    // var = sigma2 * phi.t  (reduce within 32-lane half)
    float4 pv = *(float4*)&phS[r][n0];
    float vp = pv.x * acc.x + pv.y * acc.y + pv.z * acc.z + pv.w * acc.w;
    vp += __shfl_xor(vp, 16);
    vp += __shfl_xor(vp, 8);
    vp += __shfl_xor(vp, 4);
    vp += __shfl_xor(vp, 2);
    vp += __shfl_xor(vp, 1);
    float stdv = sqrtf(fmaxf(sigma2 * vp, 0.f));
    uint2 tw;
    tw.x = pack2bf(acc.x, acc.y);
    tw.y = pack2bf(acc.z, acc.w);
    *(uint2*)&tS[r][n0] = tw;
    __syncthreads();
    // mean = t . C  (2 d's per lane), then sample + store
    float mf0 = 0.f, mf1 = 0.f;
    const ushort16* c0p = &CST[d0 * 132];
    const ushort16* c1p = &CST[(d0 + 1) * 132];
    for (int n = 0; n < MM; n += 4) {
      uint2 tn  = *(uint2*)&tS[r][n];
      uint2 cw0 = *(uint2*)&c0p[n];
      uint2 cw1 = *(uint2*)&c1p[n];
      float t0 = bf2f(tn.x & 0xffffu), t1 = bf2f(tn.x >> 16);
      float t2 = bf2f(tn.y & 0xffffu), t3 = bf2f(tn.y >> 16);
      mf0 = fmaf(t0, bf2f(cw0.x & 0xffffu), mf0);
      mf0 = fmaf(t1, bf2f(cw0.x >> 16),     mf0);
      mf0 = fmaf(t2, bf2f(cw0.y & 0xffffu), mf0);
      mf0 = fmaf(t3, bf2f(cw0.y >> 16),     mf0);
      mf1 = fmaf(t0, bf2f(cw1.x & 0xffffu), mf1);
      mf1 = fmaf(t1, bf2f(cw1.x >> 16),     mf1);
      mf1 = fmaf(t2, bf2f(cw1.y & 0xffffu), mf1);
      mf1 = fmaf(t3, bf2f(cw1.y >> 16),     mf1);
    }
    int l = l0 + r;
    float2 ev = *(const float2*)&ep[(size_t)l * DV + d0];
    float s0 = mf0 + stdv * ev.x;
    float s1 = mf1 + stdv * ev.y;
    *(uint32*)&sp[(size_t)l * HD + d0] = pack2bf(s0, s1);
  }
}

// ---------------------------------------------------------------------------
// K5: out = sfeat @ W_O_w^T + b  (32768x768x768), sfeat bf16, out fp32
// ---------------------------------------------------------------------------
__global__ __launch_bounds__(256)
void k5_out(const ushort16* __restrict__ sfeat, const float* __restrict__ Wo,
            const float* __restrict__ bias, float* __restrict__ outp) {
  __shared__ float As[16][128];
  __shared__ float Bs[16][128];
  int tid = threadIdx.x;
  int tm = blockIdx.x / 6;
  int tn = blockIdx.x % 6;
  int m0 = tm * 128, n0 = tn * 128;
  int ty = tid >> 4, tx = tid & 15;
  float acc[8][8];
#pragma unroll
  for (int i = 0; i < 8; i++)
#pragma unroll
    for (int j = 0; j < 8; j++) acc[i][j] = 0.f;

  for (int k0 = 0; k0 < HD; k0 += 16) {
    __syncthreads();
    {
      int row = tid >> 1, kh = (tid & 1) * 8;
      uint4 w = *(const uint4*)&sfeat[(size_t)(m0 + row) * HD + k0 + kh];
      As[kh + 0][row] = bf2f(w.x & 0xffffu); As[kh + 1][row] = bf2f(w.x >> 16);
      As[kh + 2][row] = bf2f(w.y & 0xffffu); As[kh + 3][row] = bf2f(w.y >> 16);
      As[kh + 4][row] = bf2f(w.z & 0xffffu); As[kh + 5][row] = bf2f(w.z >> 16);
      As[kh + 6][row] = bf2f(w.w & 0xffffu); As[kh + 7][row] = bf2f(w.w >> 16);
    }
#pragma unroll
    for (int q = 0; q < 2; q++) {
      int i = tid * 2 + q;
      int row = i >> 2, kq = i & 3;
      float4 bv = *(const float4*)&Wo[(size_t)(n0 + row) * HD + k0 + kq * 4];
      Bs[kq * 4 + 0][row] = bv.x; Bs[kq * 4 + 1][row] = bv.y;
      Bs[kq * 4 + 2][row] = bv.z; Bs[kq * 4 + 3][row] = bv.w;
    }
    __syncthreads();
#pragma unroll
    for (int k = 0; k < 16; k++) {
      float a[8], b[8];
      *(float4*)&a[0] = *(float4*)&As[k][ty * 8];
      *(float4*)&a[4] = *(float4*)&As[k][ty * 8 + 4];
      *(float4*)&b[0] = *(float4*)&Bs[k][tx * 8];
      *(float4*)&b[4] = *(float4*)&Bs[k][tx * 8 + 4];
#pragma unroll
      for (int i = 0; i < 8; i++)
#pragma unroll
        for (int j = 0; j < 8; j++) acc[i][j] = fmaf(a[i], b[j], acc[i][j]);
    }
  }
  float bs[8];
  *(float4*)&bs[0] = *(const float4*)&bias[n0 + tx * 8];
  *(float4*)&bs[4] = *(const float4*)&bias[n0 + tx * 8 + 4];
#pragma unroll
  for (int i = 0; i < 8; i++) {
    size_t base = (size_t)(m0 + ty * 8 + i) * HD + n0 + tx * 8;
    *(float4*)&outp[base]     = make_float4(acc[i][0] + bs[0], acc[i][1] + bs[1],
                                            acc[i][2] + bs[2], acc[i][3] + bs[3]);
    *(float4*)&outp[base + 4] = make_float4(acc[i][4] + bs[4], acc[i][5] + bs[5],
                                            acc[i][6] + bs[6], acc[i][7] + bs[7]);
  }
}

// ---------------------------------------------------------------------------
// K6: kl = sum(klbuf)/B  -> out[25165824]
// ---------------------------------------------------------------------------
__global__ void k6_kl(const float* __restrict__ klbuf, float* __restrict__ outp) {
  __shared__ float red[2];
  int tid = threadIdx.x;   // 128
  float s = 0.f;
  for (int e = tid; e < BH_; e += 128) s += klbuf[e];
  for (int off = 32; off >= 1; off >>= 1) s += __shfl_xor(s, off);
  if ((tid & 63) == 0) red[tid >> 6] = s;
  __syncthreads();
  if (tid == 0) outp[(size_t)B_ * L_ * HD] = (red[0] + red[1]) * (1.f / 32.f);
}

// ---------------------------------------------------------------------------
extern "C" void kernel_launch(void* const* d_in, const int* in_sizes, int n_in,
                              void* d_out, int out_size, void* d_ws, size_t ws_size,
                              hipStream_t stream) {
  (void)in_sizes; (void)n_in; (void)out_size; (void)ws_size;
  const float* x       = (const float*)d_in[0];
  const float* Wqv     = (const float*)d_in[1];
  const float* log_sf  = (const float*)d_in[2];
  const float* log_ls  = (const float*)d_in[3];
  const float* log_s2  = (const float*)d_in[4];
  const float* omega_h = (const float*)d_in[5];
  const float* phase   = (const float*)d_in[6];
  const float* Wo      = (const float*)d_in[7];
  const float* Wob     = (const float*)d_in[8];
  const float* eps     = (const float*)d_in[9];
  float* outp = (float*)d_out;

  // Workspace layout (total 188,941,824 bytes):
  char* ws = (char*)d_ws;
  ushort16* qv    = (ushort16*)(ws);                    // bf16 [b][h][l][128]  100,663,296 B
  ushort16* sfeat = (ushort16*)(ws + 100663296);        // bf16 [b][l][768]      50,331,648 B
  float*    omT   = (float*)(ws + 150994944);           // [h][m][d]                196,608 B
  float*    Gws   = (float*)(ws + 151191552);           // G, reused as Ainv     25,165,824 B
  float*    Cws   = (float*)(ws + 176357376);           // C                     12,582,912 B
  float*    klbuf = (float*)(ws + 188940288);           // per-(b,h) KL               1,536 B

  hipLaunchKernelGGL(k0_prep,  dim3(H_),      dim3(256), 0, stream, omega_h, log_ls, omT, klbuf);
  hipLaunchKernelGGL(k1_qv,    dim3(256*H_),  dim3(256), 0, stream, x, Wqv, qv);
  hipLaunchKernelGGL(k2_gram,  dim3(BH_),     dim3(256), 0, stream, qv, omT, phase, log_sf, Gws, Cws);
  hipLaunchKernelGGL(k3_factor,dim3(BH_),     dim3(256), 0, stream, Gws, Cws, log_s2, Gws, klbuf);
  hipLaunchKernelGGL(k4_sample,dim3(BH_),     dim3(256), 0, stream, qv, omT, phase, log_sf, log_s2, Gws, Cws, eps, sfeat);
  hipLaunchKernelGGL(k5_out,   dim3(256*6),   dim3(256), 0, stream, sfeat, Wo, Wob, outp);
  hipLaunchKernelGGL(k6_kl,    dim3(1),       dim3(128), 0, stream, klbuf, outp);
}

// Round 2
// 2375.220 us; speedup vs baseline: 1.8823x; 1.8823x over previous
//
#include <hip/hip_runtime.h>
#include <hip/hip_bf16.h>
#include <math.h>

// Problem constants
#define B_   32
#define L_   1024
#define H_   12
#define DV   64
#define MH   64
#define MM   128      // M = 2*Mh
#define HD   768      // hdim
#define BH_  384      // B*H

typedef unsigned int  uint32;
typedef unsigned short ushort16;
typedef __attribute__((ext_vector_type(4))) float f32x4;
typedef __attribute__((ext_vector_type(8))) short bf16x8;

__device__ __forceinline__ float bf2f(uint32 u) {
  return __uint_as_float(u << 16);
}
__device__ __forceinline__ ushort16 f2bf(float f) {
  uint32 x = __float_as_uint(f);
  x += 0x7FFFu + ((x >> 16) & 1u);   // RNE
  return (ushort16)(x >> 16);
}
__device__ __forceinline__ uint32 pack2bf(float a, float b) {
  return (uint32)f2bf(a) | ((uint32)f2bf(b) << 16);
}

// ---------------------------------------------------------------------------
// K0: convert x, Wqv to bf16; omega_scaled transposed to [h][m][d]; zero kl.
// ---------------------------------------------------------------------------
__global__ __launch_bounds__(256)
void k0_prep(const float* __restrict__ x, const float* __restrict__ Wqv,
             const float* __restrict__ omega_half, const float* __restrict__ log_ls,
             ushort16* __restrict__ xbf, ushort16* __restrict__ wqvbf,
             float* __restrict__ omT, float* __restrict__ klbuf) {
  size_t i0 = (size_t)blockIdx.x * 256 + threadIdx.x;
  size_t stride = (size_t)gridDim.x * 256;
  for (size_t i = i0; i < (size_t)25165824 / 4; i += stride) {
    float4 v = ((const float4*)x)[i];
    uint2 w; w.x = pack2bf(v.x, v.y); w.y = pack2bf(v.z, v.w);
    ((uint2*)xbf)[i] = w;
  }
  for (size_t i = i0; i < (size_t)1179648 / 4; i += stride) {
    float4 v = ((const float4*)Wqv)[i];
    uint2 w; w.x = pack2bf(v.x, v.y); w.y = pack2bf(v.z, v.w);
    ((uint2*)wqvbf)[i] = w;
  }
  if (blockIdx.x < H_) {
    int h = blockIdx.x;
    for (int e = threadIdx.x; e < MH * DV; e += blockDim.x) {
      int m = e >> 6, d = e & 63;
      float scale = 1.41421356237f * expf(-log_ls[h * DV + d]);
      omT[h * MH * DV + m * DV + d] = omega_half[h * DV * MH + d * MH + m] * scale;
    }
  }
  if (blockIdx.x == 0) {
    for (int e = threadIdx.x; e < BH_; e += blockDim.x) klbuf[e] = 0.f;
  }
}

// ---------------------------------------------------------------------------
// K1: qv = x @ Wqv^T in bf16 MFMA (16x16x32), 128x128 tile, BK=32.
//     Output bf16 permuted to [b][h][l][c], c in [0,128): c<64=q, c>=64=v.
// ---------------------------------------------------------------------------
__global__ __launch_bounds__(256)
void k1_qv_mfma(const ushort16* __restrict__ xbf, const ushort16* __restrict__ wqvbf,
                ushort16* __restrict__ qv) {
  __shared__ ushort16 As[128 * 40];
  __shared__ ushort16 Bs[128 * 40];
  int tid = threadIdx.x;
  int h  = blockIdx.x % 12;
  int tm = blockIdx.x / 12;
  int m0 = tm * 128;
  int n0 = h * 128;
  int wave = tid >> 6, lane = tid & 63;
  int wy = wave >> 1, wx = wave & 1;
  int mlane = lane & 15, q = lane >> 4;
  f32x4 acc[4][4];
#pragma unroll
  for (int i = 0; i < 4; i++)
#pragma unroll
    for (int j = 0; j < 4; j++) acc[i][j] = (f32x4){0.f, 0.f, 0.f, 0.f};

  int c0 = tid, c1 = tid + 256;
  int rowA0 = c0 >> 2, ka0 = (c0 & 3) * 8;
  int rowA1 = c1 >> 2, ka1 = (c1 & 3) * 8;

  for (int k0 = 0; k0 < HD; k0 += 32) {
    __syncthreads();
    uint4 a0 = *(const uint4*)&xbf[(size_t)(m0 + rowA0) * HD + k0 + ka0];
    uint4 a1 = *(const uint4*)&xbf[(size_t)(m0 + rowA1) * HD + k0 + ka1];
    uint4 b0 = *(const uint4*)&wqvbf[(size_t)(n0 + rowA0) * HD + k0 + ka0];
    uint4 b1 = *(const uint4*)&wqvbf[(size_t)(n0 + rowA1) * HD + k0 + ka1];
    *(uint4*)&As[rowA0 * 40 + ka0] = a0;
    *(uint4*)&As[rowA1 * 40 + ka1] = a1;
    *(uint4*)&Bs[rowA0 * 40 + ka0] = b0;
    *(uint4*)&Bs[rowA1 * 40 + ka1] = b1;
    __syncthreads();
    bf16x8 av[4], bv[4];
#pragma unroll
    for (int i = 0; i < 4; i++)
      av[i] = *(const bf16x8*)&As[(wy * 64 + i * 16 + mlane) * 40 + q * 8];
#pragma unroll
    for (int j = 0; j < 4; j++)
      bv[j] = *(const bf16x8*)&Bs[(wx * 64 + j * 16 + mlane) * 40 + q * 8];
#pragma unroll
    for (int i = 0; i < 4; i++)
#pragma unroll
      for (int j = 0; j < 4; j++)
        acc[i][j] = __builtin_amdgcn_mfma_f32_16x16x32_bf16(av[i], bv[j], acc[i][j], 0, 0, 0);
  }
#pragma unroll
  for (int i = 0; i < 4; i++) {
#pragma unroll
    for (int e = 0; e < 4; e++) {
      int gm = m0 + wy * 64 + i * 16 + q * 4 + e;
      int b = gm >> 10, l = gm & 1023;
      ushort16* dst = qv + ((((size_t)(b * 12 + h) << 10) | (unsigned)l) << 7);
#pragma unroll
      for (int j = 0; j < 4; j++) {
        int c = wx * 64 + j * 16 + mlane;
        dst[c] = f2bf(acc[i][j][e]);
      }
    }
  }
}

// ---------------------------------------------------------------------------
// K2: per (b,h): G = phi^T phi (128x128), C = phi^T v (128x64).
// ---------------------------------------------------------------------------
__global__ __launch_bounds__(256)
void k2_gram(const ushort16* __restrict__ qv, const float* __restrict__ omT,
             const float* __restrict__ phase, const float* __restrict__ log_sf,
             float* __restrict__ Gws, float* __restrict__ Cws) {
  __shared__ float OmS[MH][DV];     // [m][d]
  __shared__ float qS[32][DV];
  __shared__ float vS[32][DV];
  __shared__ float phS[32][MM];
  __shared__ float phaseS[MH];
  int bh = blockIdx.x;
  int h = bh % H_;
  int tid = threadIdx.x;
  for (int e = tid; e < MH * DV; e += 256) OmS[e >> 6][e & 63] = omT[h * MH * DV + e];
  if (tid < MH) phaseS[tid] = phase[h * MH + tid];
  float amp = sqrtf(expf(log_sf[h])) * 0.08838834764831845f;  // 1/sqrt(128)
  int ty = tid >> 4, tx = tid & 15;
  float gacc[8][8];
  float cacc[8][4];
#pragma unroll
  for (int i = 0; i < 8; i++) {
#pragma unroll
    for (int j = 0; j < 8; j++) gacc[i][j] = 0.f;
#pragma unroll
    for (int j = 0; j < 4; j++) cacc[i][j] = 0.f;
  }
  const ushort16* qp = qv + (size_t)bh * L_ * MM;

  for (int l0 = 0; l0 < L_; l0 += 32) {
    __syncthreads();
#pragma unroll
    for (int q = 0; q < 2; q++) {
      int i = tid + q * 256;           // 0..511
      int row = i >> 4, g = i & 15;
      uint4 w = *(const uint4*)&qp[(size_t)(l0 + row) * MM + g * 8];
      float f0 = bf2f(w.x & 0xffffu), f1 = bf2f(w.x >> 16);
      float f2 = bf2f(w.y & 0xffffu), f3 = bf2f(w.y >> 16);
      float f4 = bf2f(w.z & 0xffffu), f5 = bf2f(w.z >> 16);
      float f6 = bf2f(w.w & 0xffffu), f7 = bf2f(w.w >> 16);
      float* dst = (g < 8) ? &qS[row][g * 8] : &vS[row][(g - 8) * 8];
      dst[0] = f0; dst[1] = f1; dst[2] = f2; dst[3] = f3;
      dst[4] = f4; dst[5] = f5; dst[6] = f6; dst[7] = f7;
    }
    __syncthreads();
    for (int p = tid; p < 32 * MH; p += 256) {
      int r = p >> 6, m = p & 63;
      float s = phaseS[m];
#pragma unroll
      for (int d = 0; d < DV; d += 4) {
        float4 qq = *(float4*)&qS[r][d];
        float4 oo = *(float4*)&OmS[m][d];
        s = fmaf(qq.x, oo.x, s); s = fmaf(qq.y, oo.y, s);
        s = fmaf(qq.z, oo.z, s); s = fmaf(qq.w, oo.w, s);
      }
      float sv, cv;
      sincosf(s, &sv, &cv);
      phS[r][m]      = amp * cv;
      phS[r][MH + m] = amp * sv;
    }
    __syncthreads();
    for (int r = 0; r < 32; r++) {
      float a[8], b[8], vv[4];
      *(float4*)&a[0] = *(float4*)&phS[r][ty * 8];
      *(float4*)&a[4] = *(float4*)&phS[r][ty * 8 + 4];
      *(float4*)&b[0] = *(float4*)&phS[r][tx * 8];
      *(float4*)&b[4] = *(float4*)&phS[r][tx * 8 + 4];
      *(float4*)&vv[0] = *(float4*)&vS[r][tx * 4];
#pragma unroll
      for (int i = 0; i < 8; i++) {
#pragma unroll
        for (int j = 0; j < 8; j++) gacc[i][j] = fmaf(a[i], b[j], gacc[i][j]);
#pragma unroll
        for (int j = 0; j < 4; j++) cacc[i][j] = fmaf(a[i], vv[j], cacc[i][j]);
      }
    }
  }
  float* Gp = Gws + (size_t)bh * MM * MM;
#pragma unroll
  for (int i = 0; i < 8; i++) {
    int row = ty * 8 + i;
    *(float4*)&Gp[row * MM + tx * 8]     = make_float4(gacc[i][0], gacc[i][1], gacc[i][2], gacc[i][3]);
    *(float4*)&Gp[row * MM + tx * 8 + 4] = make_float4(gacc[i][4], gacc[i][5], gacc[i][6], gacc[i][7]);
  }
  float* Cp = Cws + (size_t)bh * MM * DV;
#pragma unroll
  for (int i = 0; i < 8; i++) {
    int row = ty * 8 + i;
    *(float4*)&Cp[row * DV + tx * 4] = make_float4(cacc[i][0], cacc[i][1], cacc[i][2], cacc[i][3]);
  }
}

// ---------------------------------------------------------------------------
// K3: per (b,h): blocked Cholesky (NB=16) of A = G + (s2+jit)I; blocked
//     in-place inversion X = L^-1; outputs U = X^T (dense, zeros above... below)
//     and D = X*C (over C); KL pieces. All bulk phases are register-tiled —
//     no serialized LDS RMW chains.
// ---------------------------------------------------------------------------
#define LB_(i,k) LBs[((i) << 7) + (((k) + (i)) & 127)]

__global__ __launch_bounds__(256)
void k3_factor(const float* __restrict__ Gws, float* __restrict__ Cws,
               const float* __restrict__ log_sigma2,
               float* __restrict__ Uws, float* __restrict__ klbuf) {
  __shared__ float LBs[MM * MM];     // 64 KB exactly
  int bh = blockIdx.x;
  int tid = threadIdx.x;
  float ls = log_sigma2[0];
  float sigma2 = expf(ls);
  float cjit = sigma2 + 1e-6f;
  const float* Gp = Gws + (size_t)bh * MM * MM;
  for (int e = tid; e < MM * MM; e += 256) {
    int m = e >> 7, n = e & 127;
    float g = Gp[e];
    if (m == n) g += cjit;
    LB_(m, n) = g;
  }
  float klp = 0.f;

  // ---- Phase 1: blocked right-looking Cholesky, NB=16
  for (int P = 0; P < 8; P++) {
    int p0 = P * 16;
    __syncthreads();
    // (a) 16x16 diag factor: lanes 0..15 of wave0, rows in registers
    if (tid < 16) {
      int t = tid;
      float r[16];
#pragma unroll
      for (int k = 0; k < 16; k++) r[k] = LB_(p0 + t, p0 + k);
#pragma unroll
      for (int j = 0; j < 16; j++) {
        float djj = __shfl(r[j], j);
        float sd = sqrtf(djj);
        float rinv = 1.f / sd;
        if (t == j) r[j] = sd;
        else if (t > j) r[j] *= rinv;
#pragma unroll
        for (int k2 = 0; k2 < 16; k2++) {
          if (k2 > j) {
            float lkj = __shfl(r[j], k2);
            if (t >= k2) r[k2] = fmaf(-r[j], lkj, r[k2]);
          }
        }
      }
#pragma unroll
      for (int k = 0; k < 16; k++) if (k <= t) LB_(p0 + t, p0 + k) = r[k];
      klp += 64.f * logf(r[t]);       // 32*logdetA share (logdet = 2*sum log Ljj)
    }
    __syncthreads();
    // (b) panel solve: row-parallel, in registers
    int NR = 112 - p0;
    if (NR > 0 && tid < NR) {
      int gi = p0 + 16 + tid;
      float a[16];
#pragma unroll
      for (int k = 0; k < 16; k++) a[k] = LB_(gi, p0 + k);
#pragma unroll
      for (int j = 0; j < 16; j++) {
        float inv = 1.f / LB_(p0 + j, p0 + j);
        a[j] *= inv;
#pragma unroll
        for (int k = 0; k < 16; k++)
          if (k > j) a[k] = fmaf(-a[j], LB_(p0 + k, p0 + j), a[k]);
      }
#pragma unroll
      for (int k = 0; k < 16; k++) LB_(gi, p0 + k) = a[k];
    }
    __syncthreads();
    // (c) trailing rank-16 update, register-tiled 4x4 (lower tiles only)
    int S = NR;
    if (S > 0) {
      int base = p0 + 16;
      int t4 = S >> 2;
      int ntiles = t4 * t4;
      for (int tt = tid; tt < ntiles; tt += 256) {
        int ti = tt / t4, tj = tt % t4;
        if (ti < tj) continue;
        int gi = base + ti * 4, gj = base + tj * 4;
        float acc[4][4] = {};
#pragma unroll
        for (int j = 0; j < 16; j++) {
          float pa[4], pb[4];
#pragma unroll
          for (int a2 = 0; a2 < 4; a2++) pa[a2] = LB_(gi + a2, p0 + j);
#pragma unroll
          for (int b2 = 0; b2 < 4; b2++) pb[b2] = LB_(gj + b2, p0 + j);
#pragma unroll
          for (int a2 = 0; a2 < 4; a2++)
#pragma unroll
            for (int b2 = 0; b2 < 4; b2++)
              acc[a2][b2] = fmaf(pa[a2], pb[b2], acc[a2][b2]);
        }
#pragma unroll
        for (int a2 = 0; a2 < 4; a2++)
#pragma unroll
          for (int b2 = 0; b2 < 4; b2++)
            LB_(gi + a2, gj + b2) -= acc[a2][b2];
      }
    }
  }
  __syncthreads();

  // ---- Phase 2: invert the 8 diag blocks in place (zero-filled upper)
  {
    float xk[16];
    int cb = tid >> 4, cc = tid & 15;
    if (tid < 128) {
      int g = cb * 16;
#pragma unroll
      for (int rr = 0; rr < 16; rr++) {
        float s = (rr == cc) ? 1.f : 0.f;
#pragma unroll
        for (int k = 0; k < 16; k++)
          if (k < rr) s = fmaf(-LB_(g + rr, g + k), xk[k], s);
        xk[rr] = (rr >= cc) ? s / LB_(g + rr, g + rr) : 0.f;
      }
    }
    __syncthreads();
    if (tid < 128) {
      int g = cb * 16;
#pragma unroll
      for (int rr = 0; rr < 16; rr++) LB_(g + rr, g + cc) = xk[rr];
    }
    __syncthreads();
  }

  // ---- Phase 3: off-diag blocks of X = L^-1, block-column right-to-left.
  //  Step A: Y_KJ = L_KJ * X_JJ (in place over L_KJ)
  //  Step B: X_IJ = -sum_{K=J+1..I} X_IK * Y_KJ (in place over Y)
  {
    int r16 = tid >> 4, c16 = tid & 15;
    for (int J = 6; J >= 0; J--) {
      int nb = 7 - J;
      float yv[7];
#pragma unroll
      for (int q = 0; q < 7; q++) {
        if (q < nb) {
          int K = J + 1 + q;
          float s = 0.f;
#pragma unroll
          for (int c2 = 0; c2 < 16; c2++)
            s = fmaf(LB_(K * 16 + r16, J * 16 + c2), LB_(J * 16 + c2, J * 16 + c16), s);
          yv[q] = s;
        }
      }
      __syncthreads();
#pragma unroll
      for (int q = 0; q < 7; q++)
        if (q < nb) LB_((J + 1 + q) * 16 + r16, J * 16 + c16) = yv[q];
      __syncthreads();
      float xv[7];
#pragma unroll
      for (int q = 0; q < 7; q++) {
        if (q < nb) {
          int I = J + 1 + q;
          float s = 0.f;
          for (int K = J + 1; K <= I; K++) {
#pragma unroll
            for (int k = 0; k < 16; k++)
              s = fmaf(LB_(I * 16 + r16, K * 16 + k), LB_(K * 16 + k, J * 16 + c16), s);
          }
          xv[q] = -s;
        }
      }
      __syncthreads();
#pragma unroll
      for (int q = 0; q < 7; q++)
        if (q < nb) LB_((J + 1 + q) * 16 + r16, J * 16 + c16) = xv[q];
      __syncthreads();
    }
  }

  // ---- Phase 4: write U = X^T (row-major [m][n], zeros for n<m); tr(Ainv)
  float* Up = Uws + (size_t)bh * MM * MM;
  for (int e = tid; e < MM * MM; e += 256) {
    int m = e >> 7, n = e & 127;
    float xv2 = (n >= m) ? LB_(n, m) : 0.f;
    Up[e] = xv2;
    klp += 32.f * sigma2 * xv2 * xv2;   // 0.5*Dv*sigma2*tr(Ainv), tr = ||X||_F^2
  }

  // ---- Phase 5: D = X * C, in place over C (buffer in regs, barrier, write)
  float* Cp = Cws + (size_t)bh * MM * DV;
  {
    float dv[32];
#pragma unroll
    for (int t = 0; t < 32; t++) {
      int e = tid + (t << 8);
      int n = e >> 6, d = e & 63;
      float s = 0.f;
      for (int m = 0; m <= n; m++)
        s = fmaf(LB_(n, m), Cp[(m << 6) + d], s);
      dv[t] = s;
    }
    __syncthreads();
#pragma unroll
    for (int t = 0; t < 32; t++) Cp[tid + (t << 8)] = dv[t];
    __syncthreads();
  }

  // ---- Phase 6: mu_norm2 = ||X^T D||_F^2
  for (int t = 0; t < 32; t++) {
    int e = tid + (t << 8);
    int m = e >> 6, d = e & 63;
    float s = 0.f;
    for (int n = m; n < MM; n++)
      s = fmaf(LB_(n, m), Cp[(n << 6) + d], s);
    klp += 0.5f * s * s;
  }
  if (tid == 0) klp += -4096.f - 4096.f * ls;   // 0.5*(-k - Dv*M*log(sigma2))
  atomicAdd(&klbuf[bh], klp);
}

// ---------------------------------------------------------------------------
// K4: per (b,h) row l: recompute phi; z = X*phi via U (z_n = sum_m U[m][n]phi_m);
//     var = sigma2*||z||^2; mean = z . D; sfeat = mean + sqrt(var)*eps (bf16).
// ---------------------------------------------------------------------------
__global__ __launch_bounds__(256)
void k4_sample(const ushort16* __restrict__ qv, const float* __restrict__ omT,
               const float* __restrict__ phase, const float* __restrict__ log_sf,
               const float* __restrict__ log_sigma2,
               const float* __restrict__ Uws, const float* __restrict__ Dws,
               const float* __restrict__ eps, ushort16* __restrict__ sfeat) {
  __shared__ ushort16 US[MM * MM];         // 32768 B, bf16  (U = X^T, [m][n])
  __shared__ ushort16 DST[DV * 132];       // 16896 B, bf16, [d][n] stride 132
  __shared__ ushort16 OmS[MH * DV];        // 8192 B, bf16, [m][d]
  __shared__ float    phS[8][MM];          // 4096 B
  __shared__ ushort16 tS[8][MM];           // 2048 B, bf16 (z rows)
  __shared__ float    phaseS[MH];          // 256 B  -> total 64256 B
  int bh = blockIdx.x;
  int h = bh % H_;
  int b = bh / H_;
  int tid = threadIdx.x;
  const float* Up = Uws + (size_t)bh * MM * MM;
  for (int e = tid; e < MM * MM; e += 256) US[e] = f2bf(Up[e]);
  const float* Dp = Dws + (size_t)bh * MM * DV;
  for (int e = tid; e < MM * DV; e += 256) {
    int d = e >> 7, n = e & 127;
    DST[d * 132 + n] = f2bf(Dp[n * DV + d]);
  }
  for (int e = tid; e < MH * DV; e += 256) OmS[e] = f2bf(omT[h * MH * DV + e]);
  if (tid < MH) phaseS[tid] = phase[h * MH + tid];
  float amp = sqrtf(expf(log_sf[h])) * 0.08838834764831845f;
  float sigma2 = expf(log_sigma2[0]);
  const ushort16* qp = qv + (size_t)bh * L_ * MM;
  const float* ep = eps + (size_t)bh * L_ * DV;
  ushort16* sp = sfeat + ((size_t)b * L_ * HD + h * DV);
  int lane = tid & 63;
  int half = lane & 31;
  int r = tid >> 5;          // row-in-chunk, 0..7 (one 32-lane half per row)
  int n0 = half * 4;
  int d0 = half * 2;

  for (int l0 = 0; l0 < L_; l0 += 8) {
    __syncthreads();
    // phi for 8 rows (512 proj values, 2 per thread)
#pragma unroll
    for (int q = 0; q < 2; q++) {
      int p = tid + q * 256;
      int rr = p >> 6, m = p & 63;
      const ushort16* qrow = &qp[(size_t)(l0 + rr) * MM];
      float s = phaseS[m];
#pragma unroll
      for (int d = 0; d < DV; d += 8) {
        uint4 qw = *(const uint4*)&qrow[d];
        uint4 ow = *(const uint4*)&OmS[m * DV + d];
        s = fmaf(bf2f(qw.x & 0xffffu), bf2f(ow.x & 0xffffu), s);
        s = fmaf(bf2f(qw.x >> 16),     bf2f(ow.x >> 16),     s);
        s = fmaf(bf2f(qw.y & 0xffffu), bf2f(ow.y & 0xffffu), s);
        s = fmaf(bf2f(qw.y >> 16),     bf2f(ow.y >> 16),     s);
        s = fmaf(bf2f(qw.z & 0xffffu), bf2f(ow.z & 0xffffu), s);
        s = fmaf(bf2f(qw.z >> 16),     bf2f(ow.z >> 16),     s);
        s = fmaf(bf2f(qw.w & 0xffffu), bf2f(ow.w & 0xffffu), s);
        s = fmaf(bf2f(qw.w >> 16),     bf2f(ow.w >> 16),     s);
      }
      float sv, cv;
      sincosf(s, &sv, &cv);
      phS[rr][m]      = amp * cv;
      phS[rr][MH + m] = amp * sv;
    }
    __syncthreads();
    // z = X*phi: z_n = sum_m U[m][n] phi_m  (4 n's per lane)
    float4 acc = make_float4(0.f, 0.f, 0.f, 0.f);
    for (int m = 0; m < MM; m += 4) {
      float4 ph = *(float4*)&phS[r][m];
      uint2 a0 = *(uint2*)&US[(m + 0) * MM + n0];
      uint2 a1 = *(uint2*)&US[(m + 1) * MM + n0];
      uint2 a2 = *(uint2*)&US[(m + 2) * MM + n0];
      uint2 a3 = *(uint2*)&US[(m + 3) * MM + n0];
      acc.x = fmaf(ph.x, bf2f(a0.x & 0xffffu), acc.x);
      acc.y = fmaf(ph.x, bf2f(a0.x >> 16),     acc.y);
      acc.z = fmaf(ph.x, bf2f(a0.y & 0xffffu), acc.z);
      acc.w = fmaf(ph.x, bf2f(a0.y >> 16),     acc.w);
      acc.x = fmaf(ph.y, bf2f(a1.x & 0xffffu), acc.x);
      acc.y = fmaf(ph.y, bf2f(a1.x >> 16),     acc.y);
      acc.z = fmaf(ph.y, bf2f(a1.y & 0xffffu), acc.z);
      acc.w = fmaf(ph.y, bf2f(a1.y >> 16),     acc.w);
      acc.x = fmaf(ph.z, bf2f(a2.x & 0xffffu), acc.x);
      acc.y = fmaf(ph.z, bf2f(a2.x >> 16),     acc.y);
      acc.z = fmaf(ph.z, bf2f(a2.y & 0xffffu), acc.z);
      acc.w = fmaf(ph.z, bf2f(a2.y >> 16),     acc.w);
      acc.x = fmaf(ph.w, bf2f(a3.x & 0xffffu), acc.x);
      acc.y = fmaf(ph.w, bf2f(a3.x >> 16),     acc.y);
      acc.z = fmaf(ph.w, bf2f(a3.y & 0xffffu), acc.z);
      acc.w = fmaf(ph.w, bf2f(a3.y >> 16),     acc.w);
    }
    // var = sigma2 * ||z||^2 (reduce within 32-lane half)
    float vp = acc.x * acc.x + acc.y * acc.y + acc.z * acc.z + acc.w * acc.w;
    vp += __shfl_xor(vp, 16);
    vp += __shfl_xor(vp, 8);
    vp += __shfl_xor(vp, 4);
    vp += __shfl_xor(vp, 2);
    vp += __shfl_xor(vp, 1);
    float stdv = sqrtf(fmaxf(sigma2 * vp, 0.f));
    uint2 tw;
    tw.x = pack2bf(acc.x, acc.y);
    tw.y = pack2bf(acc.z, acc.w);
    *(uint2*)&tS[r][n0] = tw;
    __syncthreads();
    // mean = z . D  (2 d's per lane), then sample + store
    float mf0 = 0.f, mf1 = 0.f;
    const ushort16* c0p = &DST[d0 * 132];
    const ushort16* c1p = &DST[(d0 + 1) * 132];
    for (int n = 0; n < MM; n += 4) {
      uint2 tn  = *(uint2*)&tS[r][n];
      uint2 cw0 = *(uint2*)&c0p[n];
      uint2 cw1 = *(uint2*)&c1p[n];
      float t0 = bf2f(tn.x & 0xffffu), t1 = bf2f(tn.x >> 16);
      float t2 = bf2f(tn.y & 0xffffu), t3 = bf2f(tn.y >> 16);
      mf0 = fmaf(t0, bf2f(cw0.x & 0xffffu), mf0);
      mf0 = fmaf(t1, bf2f(cw0.x >> 16),     mf0);
      mf0 = fmaf(t2, bf2f(cw0.y & 0xffffu), mf0);
      mf0 = fmaf(t3, bf2f(cw0.y >> 16),     mf0);
      mf1 = fmaf(t0, bf2f(cw1.x & 0xffffu), mf1);
      mf1 = fmaf(t1, bf2f(cw1.x >> 16),     mf1);
      mf1 = fmaf(t2, bf2f(cw1.y & 0xffffu), mf1);
      mf1 = fmaf(t3, bf2f(cw1.y >> 16),     mf1);
    }
    int l = l0 + r;
    float2 ev = *(const float2*)&ep[(size_t)l * DV + d0];
    float s0 = mf0 + stdv * ev.x;
    float s1 = mf1 + stdv * ev.y;
    *(uint32*)&sp[(size_t)l * HD + d0] = pack2bf(s0, s1);
  }
}

// ---------------------------------------------------------------------------
// K5: out = sfeat @ Wo^T + b, bf16 MFMA (Wo converted during staging), fp32 out
// ---------------------------------------------------------------------------
__global__ __launch_bounds__(256)
void k5_out_mfma(const ushort16* __restrict__ sfeat, const float* __restrict__ Wo,
                 const float* __restrict__ bias, float* __restrict__ outp) {
  __shared__ ushort16 As[128 * 40];
  __shared__ ushort16 Bs[128 * 40];
  int tid = threadIdx.x;
  int tn = blockIdx.x % 6;
  int tm = blockIdx.x / 6;
  int m0 = tm * 128, n0 = tn * 128;
  int wave = tid >> 6, lane = tid & 63;
  int wy = wave >> 1, wx = wave & 1;
  int mlane = lane & 15, q = lane >> 4;
  f32x4 acc[4][4];
#pragma unroll
  for (int i = 0; i < 4; i++)
#pragma unroll
    for (int j = 0; j < 4; j++) acc[i][j] = (f32x4){0.f, 0.f, 0.f, 0.f};

  int c0 = tid, c1 = tid + 256;
  int rowA0 = c0 >> 2, ka0 = (c0 & 3) * 8;
  int rowA1 = c1 >> 2, ka1 = (c1 & 3) * 8;

  for (int k0 = 0; k0 < HD; k0 += 32) {
    __syncthreads();
    uint4 a0 = *(const uint4*)&sfeat[(size_t)(m0 + rowA0) * HD + k0 + ka0];
    uint4 a1 = *(const uint4*)&sfeat[(size_t)(m0 + rowA1) * HD + k0 + ka1];
    float4 w00 = *(const float4*)&Wo[(size_t)(n0 + rowA0) * HD + k0 + ka0];
    float4 w01 = *(const float4*)&Wo[(size_t)(n0 + rowA0) * HD + k0 + ka0 + 4];
    float4 w10 = *(const float4*)&Wo[(size_t)(n0 + rowA1) * HD + k0 + ka1];
    float4 w11 = *(const float4*)&Wo[(size_t)(n0 + rowA1) * HD + k0 + ka1 + 4];
    uint4 b0, b1;
    b0.x = pack2bf(w00.x, w00.y); b0.y = pack2bf(w00.z, w00.w);
    b0.z = pack2bf(w01.x, w01.y); b0.w = pack2bf(w01.z, w01.w);
    b1.x = pack2bf(w10.x, w10.y); b1.y = pack2bf(w10.z, w10.w);
    b1.z = pack2bf(w11.x, w11.y); b1.w = pack2bf(w11.z, w11.w);
    *(uint4*)&As[rowA0 * 40 + ka0] = a0;
    *(uint4*)&As[rowA1 * 40 + ka1] = a1;
    *(uint4*)&Bs[rowA0 * 40 + ka0] = b0;
    *(uint4*)&Bs[rowA1 * 40 + ka1] = b1;
    __syncthreads();
    bf16x8 av[4], bv[4];
#pragma unroll
    for (int i = 0; i < 4; i++)
      av[i] = *(const bf16x8*)&As[(wy * 64 + i * 16 + mlane) * 40 + q * 8];
#pragma unroll
    for (int j = 0; j < 4; j++)
      bv[j] = *(const bf16x8*)&Bs[(wx * 64 + j * 16 + mlane) * 40 + q * 8];
#pragma unroll
    for (int i = 0; i < 4; i++)
#pragma unroll
      for (int j = 0; j < 4; j++)
        acc[i][j] = __builtin_amdgcn_mfma_f32_16x16x32_bf16(av[i], bv[j], acc[i][j], 0, 0, 0);
  }
  float bsv[4];
#pragma unroll
  for (int j = 0; j < 4; j++) bsv[j] = bias[n0 + wx * 64 + j * 16 + mlane];
#pragma unroll
  for (int i = 0; i < 4; i++) {
#pragma unroll
    for (int e = 0; e < 4; e++) {
      int gm = m0 + wy * 64 + i * 16 + q * 4 + e;
#pragma unroll
      for (int j = 0; j < 4; j++) {
        int gn = n0 + wx * 64 + j * 16 + mlane;
        outp[(size_t)gm * HD + gn] = acc[i][j][e] + bsv[j];
      }
    }
  }
}

// ---------------------------------------------------------------------------
// K6: kl = sum(klbuf)/B  -> out[25165824]
// ---------------------------------------------------------------------------
__global__ void k6_kl(const float* __restrict__ klbuf, float* __restrict__ outp) {
  __shared__ float red[2];
  int tid = threadIdx.x;   // 128
  float s = 0.f;
  for (int e = tid; e < BH_; e += 128) s += klbuf[e];
  for (int off = 32; off >= 1; off >>= 1) s += __shfl_xor(s, off);
  if ((tid & 63) == 0) red[tid >> 6] = s;
  __syncthreads();
  if (tid == 0) outp[(size_t)B_ * L_ * HD] = (red[0] + red[1]) * (1.f / 32.f);
}

// ---------------------------------------------------------------------------
extern "C" void kernel_launch(void* const* d_in, const int* in_sizes, int n_in,
                              void* d_out, int out_size, void* d_ws, size_t ws_size,
                              hipStream_t stream) {
  (void)in_sizes; (void)n_in; (void)out_size; (void)ws_size;
  const float* x       = (const float*)d_in[0];
  const float* Wqv     = (const float*)d_in[1];
  const float* log_sf  = (const float*)d_in[2];
  const float* log_ls  = (const float*)d_in[3];
  const float* log_s2  = (const float*)d_in[4];
  const float* omega_h = (const float*)d_in[5];
  const float* phase   = (const float*)d_in[6];
  const float* Wo      = (const float*)d_in[7];
  const float* Wob     = (const float*)d_in[8];
  const float* eps     = (const float*)d_in[9];
  float* outp = (float*)d_out;

  // Workspace layout (total 188,941,824 bytes):
  char* ws = (char*)d_ws;
  ushort16* qv    = (ushort16*)(ws);                    // bf16 [b][h][l][128]  100,663,296 B
  ushort16* xbf   = (ushort16*)(ws + 100663296);        // bf16 x; later sfeat   50,331,648 B
  ushort16* sfeat = xbf;                                // alias (k1 done with xbf before k4)
  float*    omT   = (float*)(ws + 150994944);           // [h][m][d]                196,608 B
  float*    Gws   = (float*)(ws + 151191552);           // G -> U; wqvbf at head 25,165,824 B
  ushort16* wqvbf = (ushort16*)(ws + 151191552);        // bf16 Wqv (pre-k2 only) 2,359,296 B
  float*    Cws   = (float*)(ws + 176357376);           // C -> D                12,582,912 B
  float*    klbuf = (float*)(ws + 188940288);           // per-(b,h) KL               1,536 B

  hipLaunchKernelGGL(k0_prep,    dim3(1024),   dim3(256), 0, stream, x, Wqv, omega_h, log_ls, xbf, wqvbf, omT, klbuf);
  hipLaunchKernelGGL(k1_qv_mfma, dim3(3072),   dim3(256), 0, stream, xbf, wqvbf, qv);
  hipLaunchKernelGGL(k2_gram,    dim3(BH_),    dim3(256), 0, stream, qv, omT, phase, log_sf, Gws, Cws);
  hipLaunchKernelGGL(k3_factor,  dim3(BH_),    dim3(256), 0, stream, Gws, Cws, log_s2, Gws, klbuf);
  hipLaunchKernelGGL(k4_sample,  dim3(BH_),    dim3(256), 0, stream, qv, omT, phase, log_sf, log_s2, Gws, Cws, eps, sfeat);
  hipLaunchKernelGGL(k5_out_mfma,dim3(1536),   dim3(256), 0, stream, sfeat, Wo, Wob, outp);
  hipLaunchKernelGGL(k6_kl,      dim3(1),      dim3(128), 0, stream, klbuf, outp);
}

// Round 3
// 1135.272 us; speedup vs baseline: 3.9382x; 2.0922x over previous
//
#include <hip/hip_runtime.h>
#include <hip/hip_bf16.h>
#include <math.h>

// Problem constants
#define B_   32
#define L_   1024
#define H_   12
#define DV   64
#define MH   64
#define MM   128      // M = 2*Mh
#define HD   768      // hdim
#define BH_  384      // B*H

typedef unsigned int  uint32;
typedef unsigned short ushort16;
typedef __attribute__((ext_vector_type(4))) float f32x4;
typedef __attribute__((ext_vector_type(8))) short bf16x8;

__device__ __forceinline__ float bf2f(uint32 u) {
  return __uint_as_float(u << 16);
}
__device__ __forceinline__ ushort16 f2bf(float f) {
  uint32 x = __float_as_uint(f);
  x += 0x7FFFu + ((x >> 16) & 1u);   // RNE
  return (ushort16)(x >> 16);
}
__device__ __forceinline__ uint32 pack2bf(float a, float b) {
  return (uint32)f2bf(a) | ((uint32)f2bf(b) << 16);
}

// ---------------------------------------------------------------------------
// K0: convert x, Wqv to bf16; omega_scaled bf16 [h][m][d]; zero kl.
// ---------------------------------------------------------------------------
__global__ __launch_bounds__(256)
void k0_prep(const float* __restrict__ x, const float* __restrict__ Wqv,
             const float* __restrict__ omega_half, const float* __restrict__ log_ls,
             ushort16* __restrict__ xbf, ushort16* __restrict__ wqvbf,
             ushort16* __restrict__ omTbf, float* __restrict__ klbuf) {
  size_t i0 = (size_t)blockIdx.x * 256 + threadIdx.x;
  size_t stride = (size_t)gridDim.x * 256;
  for (size_t i = i0; i < (size_t)25165824 / 4; i += stride) {
    float4 v = ((const float4*)x)[i];
    uint2 w; w.x = pack2bf(v.x, v.y); w.y = pack2bf(v.z, v.w);
    ((uint2*)xbf)[i] = w;
  }
  for (size_t i = i0; i < (size_t)1179648 / 4; i += stride) {
    float4 v = ((const float4*)Wqv)[i];
    uint2 w; w.x = pack2bf(v.x, v.y); w.y = pack2bf(v.z, v.w);
    ((uint2*)wqvbf)[i] = w;
  }
  if (blockIdx.x < H_) {
    int h = blockIdx.x;
    for (int e = threadIdx.x; e < MH * DV; e += blockDim.x) {
      int m = e >> 6, d = e & 63;
      float scale = 1.41421356237f * expf(-log_ls[h * DV + d]);
      omTbf[h * MH * DV + m * DV + d] = f2bf(omega_half[h * DV * MH + d * MH + m] * scale);
    }
  }
  if (blockIdx.x == 0) {
    for (int e = threadIdx.x; e < BH_; e += blockDim.x) klbuf[e] = 0.f;
  }
}

// ---------------------------------------------------------------------------
// K1: qv = x @ Wqv^T in bf16 MFMA (16x16x32), 128x128 tile, BK=32.
//     Output bf16 permuted to [b][h][l][c], c in [0,128): c<64=q, c>=64=v.
// ---------------------------------------------------------------------------
__global__ __launch_bounds__(256)
void k1_qv_mfma(const ushort16* __restrict__ xbf, const ushort16* __restrict__ wqvbf,
                ushort16* __restrict__ qv) {
  __shared__ ushort16 As[128 * 40];
  __shared__ ushort16 Bs[128 * 40];
  int tid = threadIdx.x;
  int h  = blockIdx.x % 12;
  int tm = blockIdx.x / 12;
  int m0 = tm * 128;
  int n0 = h * 128;
  int wave = tid >> 6, lane = tid & 63;
  int wy = wave >> 1, wx = wave & 1;
  int mlane = lane & 15, q = lane >> 4;
  f32x4 acc[4][4];
#pragma unroll
  for (int i = 0; i < 4; i++)
#pragma unroll
    for (int j = 0; j < 4; j++) acc[i][j] = (f32x4){0.f, 0.f, 0.f, 0.f};

  int c0 = tid, c1 = tid + 256;
  int rowA0 = c0 >> 2, ka0 = (c0 & 3) * 8;
  int rowA1 = c1 >> 2, ka1 = (c1 & 3) * 8;

  for (int k0 = 0; k0 < HD; k0 += 32) {
    __syncthreads();
    uint4 a0 = *(const uint4*)&xbf[(size_t)(m0 + rowA0) * HD + k0 + ka0];
    uint4 a1 = *(const uint4*)&xbf[(size_t)(m0 + rowA1) * HD + k0 + ka1];
    uint4 b0 = *(const uint4*)&wqvbf[(size_t)(n0 + rowA0) * HD + k0 + ka0];
    uint4 b1 = *(const uint4*)&wqvbf[(size_t)(n0 + rowA1) * HD + k0 + ka1];
    *(uint4*)&As[rowA0 * 40 + ka0] = a0;
    *(uint4*)&As[rowA1 * 40 + ka1] = a1;
    *(uint4*)&Bs[rowA0 * 40 + ka0] = b0;
    *(uint4*)&Bs[rowA1 * 40 + ka1] = b1;
    __syncthreads();
    bf16x8 av[4], bv[4];
#pragma unroll
    for (int i = 0; i < 4; i++)
      av[i] = *(const bf16x8*)&As[(wy * 64 + i * 16 + mlane) * 40 + q * 8];
#pragma unroll
    for (int j = 0; j < 4; j++)
      bv[j] = *(const bf16x8*)&Bs[(wx * 64 + j * 16 + mlane) * 40 + q * 8];
#pragma unroll
    for (int i = 0; i < 4; i++)
#pragma unroll
      for (int j = 0; j < 4; j++)
        acc[i][j] = __builtin_amdgcn_mfma_f32_16x16x32_bf16(av[i], bv[j], acc[i][j], 0, 0, 0);
  }
#pragma unroll
  for (int i = 0; i < 4; i++) {
#pragma unroll
    for (int e = 0; e < 4; e++) {
      int gm = m0 + wy * 64 + i * 16 + q * 4 + e;
      int b = gm >> 10, l = gm & 1023;
      ushort16* dst = qv + ((((size_t)(b * 12 + h) << 10) | (unsigned)l) << 7);
#pragma unroll
      for (int j = 0; j < 4; j++) {
        int c = wx * 64 + j * 16 + mlane;
        dst[c] = f2bf(acc[i][j][e]);
      }
    }
  }
}

// ---------------------------------------------------------------------------
// K2: per (b,h): G = phi^T phi (128x128), C = phi^T v (128x64), all MFMA.
//     phi computed via MFMA (proj = q @ Om^T), sincos on C-layout regs,
//     stored TRANSPOSED (PhT[m][l]) so G/C A-B frags are row-reads.
// ---------------------------------------------------------------------------
__global__ __launch_bounds__(256)
void k2_gram_mfma(const ushort16* __restrict__ qv, const ushort16* __restrict__ omTbf,
                  const float* __restrict__ phase, const float* __restrict__ log_sf,
                  char* __restrict__ Gbase, float* __restrict__ Cws) {
  __shared__ ushort16 PhT[128 * 136];   // 34816 B  phi^T [m][l]
  __shared__ ushort16 vT[64 * 136];     // 17408 B  v^T   [d][l]
  __shared__ float phaseS[MH];
  int bh = blockIdx.x;
  int h = bh % H_;
  int tid = threadIdx.x;
  int wave = tid >> 6, lane = tid & 63;
  int ml = lane & 15, qq = lane >> 4;
  if (tid < MH) phaseS[tid] = phase[h * MH + tid];
  float amp = sqrtf(expf(log_sf[h])) * 0.08838834764831845f;  // 1/sqrt(128)
  const ushort16* qp = qv + (size_t)bh * L_ * MM;
  const ushort16* Om = omTbf + h * MH * DV;
  f32x4 gacc[2][8];
  f32x4 cacc[2][4];
#pragma unroll
  for (int i = 0; i < 2; i++) {
#pragma unroll
    for (int j = 0; j < 8; j++) gacc[i][j] = (f32x4){0.f, 0.f, 0.f, 0.f};
#pragma unroll
    for (int j = 0; j < 4; j++) cacc[i][j] = (f32x4){0.f, 0.f, 0.f, 0.f};
  }
  __syncthreads();   // phaseS ready

  for (int l0 = 0; l0 < L_; l0 += 128) {
    // MFMA1: proj for this wave's 32 rows (K=64)
    f32x4 pacc[2][4];
#pragma unroll
    for (int i = 0; i < 2; i++)
#pragma unroll
      for (int j = 0; j < 4; j++) pacc[i][j] = (f32x4){0.f, 0.f, 0.f, 0.f};
#pragma unroll
    for (int k = 0; k < 2; k++) {
      bf16x8 af[2], bfm[4];
#pragma unroll
      for (int i = 0; i < 2; i++)
        af[i] = *(const bf16x8*)&qp[(size_t)(l0 + wave * 32 + i * 16 + ml) * MM + k * 32 + qq * 8];
#pragma unroll
      for (int j = 0; j < 4; j++)
        bfm[j] = *(const bf16x8*)&Om[(j * 16 + ml) * DV + k * 32 + qq * 8];
#pragma unroll
      for (int i = 0; i < 2; i++)
#pragma unroll
        for (int j = 0; j < 4; j++)
          pacc[i][j] = __builtin_amdgcn_mfma_f32_16x16x32_bf16(af[i], bfm[j], pacc[i][j], 0, 0, 0);
    }
    // stage v^T
    for (int u = tid; u < 1024; u += 256) {
      int row = u >> 3, g = u & 7;
      uint4 w = *(const uint4*)&qp[(size_t)(l0 + row) * MM + 64 + g * 8];
      vT[(g * 8 + 0) * 136 + row] = (ushort16)(w.x & 0xffffu);
      vT[(g * 8 + 1) * 136 + row] = (ushort16)(w.x >> 16);
      vT[(g * 8 + 2) * 136 + row] = (ushort16)(w.y & 0xffffu);
      vT[(g * 8 + 3) * 136 + row] = (ushort16)(w.y >> 16);
      vT[(g * 8 + 4) * 136 + row] = (ushort16)(w.z & 0xffffu);
      vT[(g * 8 + 5) * 136 + row] = (ushort16)(w.z >> 16);
      vT[(g * 8 + 6) * 136 + row] = (ushort16)(w.w & 0xffffu);
      vT[(g * 8 + 7) * 136 + row] = (ushort16)(w.w >> 16);
    }
    // phi (transposed store)
#pragma unroll
    for (int i = 0; i < 2; i++)
#pragma unroll
      for (int j = 0; j < 4; j++)
#pragma unroll
        for (int e = 0; e < 4; e++) {
          int l = wave * 32 + i * 16 + qq * 4 + e;   // local row
          int m = j * 16 + ml;
          float s = pacc[i][j][e] + phaseS[m];
          float sv, cv;
          sincosf(s, &sv, &cv);
          PhT[m * 136 + l]        = f2bf(amp * cv);
          PhT[(MH + m) * 136 + l] = f2bf(amp * sv);
        }
    __syncthreads();
    // G += PhT . PhT^T ; C += PhT . vT^T   (K = 128 local l)
#pragma unroll
    for (int k = 0; k < 4; k++) {
      bf16x8 af[2];
#pragma unroll
      for (int i = 0; i < 2; i++)
        af[i] = *(const bf16x8*)&PhT[(wave * 32 + i * 16 + ml) * 136 + k * 32 + qq * 8];
#pragma unroll
      for (int j = 0; j < 8; j++) {
        bf16x8 bfr = *(const bf16x8*)&PhT[(j * 16 + ml) * 136 + k * 32 + qq * 8];
#pragma unroll
        for (int i = 0; i < 2; i++)
          gacc[i][j] = __builtin_amdgcn_mfma_f32_16x16x32_bf16(af[i], bfr, gacc[i][j], 0, 0, 0);
      }
#pragma unroll
      for (int j = 0; j < 4; j++) {
        bf16x8 bvr = *(const bf16x8*)&vT[(j * 16 + ml) * 136 + k * 32 + qq * 8];
#pragma unroll
        for (int i = 0; i < 2; i++)
          cacc[i][j] = __builtin_amdgcn_mfma_f32_16x16x32_bf16(af[i], bvr, cacc[i][j], 0, 0, 0);
      }
    }
    __syncthreads();
  }
  float* Gp = (float*)(Gbase + (size_t)bh * 65536);
#pragma unroll
  for (int i = 0; i < 2; i++)
#pragma unroll
    for (int e = 0; e < 4; e++) {
      int m = wave * 32 + i * 16 + qq * 4 + e;
#pragma unroll
      for (int j = 0; j < 8; j++) Gp[m * MM + j * 16 + ml] = gacc[i][j][e];
    }
  float* Cp = Cws + (size_t)bh * MM * DV;
#pragma unroll
  for (int i = 0; i < 2; i++)
#pragma unroll
    for (int e = 0; e < 4; e++) {
      int m = wave * 32 + i * 16 + qq * 4 + e;
#pragma unroll
      for (int j = 0; j < 4; j++) Cp[m * DV + j * 16 + ml] = cacc[i][j][e];
    }
}

// ---------------------------------------------------------------------------
// K3: per (b,h): blocked Cholesky (NB=16); blocked inversion X = L^-1;
//     outputs Xbf (bf16 lower-tri row-major [n][m]) and DTbf (bf16 D^T [d][n])
//     into the G slot; D = X*C fp32 in place over C; KL pieces.
// ---------------------------------------------------------------------------
#define LB_(i,k) LBs[((i) << 7) + (((k) + (i)) & 127)]

__global__ __launch_bounds__(256)
void k3_factor(char* __restrict__ Gbase, float* __restrict__ Cws,
               const float* __restrict__ log_sigma2, float* __restrict__ klbuf) {
  __shared__ float LBs[MM * MM];     // 64 KB exactly
  int bh = blockIdx.x;
  int tid = threadIdx.x;
  float ls = log_sigma2[0];
  float sigma2 = expf(ls);
  float cjit = sigma2 + 1e-6f;
  const float* Gp = (const float*)(Gbase + (size_t)bh * 65536);
  for (int e = tid; e < MM * MM; e += 256) {
    int m = e >> 7, n = e & 127;
    float g = Gp[e];
    if (m == n) g += cjit;
    LB_(m, n) = g;
  }
  float klp = 0.f;

  // ---- Phase 1: blocked right-looking Cholesky, NB=16
  for (int P = 0; P < 8; P++) {
    int p0 = P * 16;
    __syncthreads();
    if (tid < 16) {
      int t = tid;
      float r[16];
#pragma unroll
      for (int k = 0; k < 16; k++) r[k] = LB_(p0 + t, p0 + k);
#pragma unroll
      for (int j = 0; j < 16; j++) {
        float djj = __shfl(r[j], j);
        float sd = sqrtf(djj);
        float rinv = 1.f / sd;
        if (t == j) r[j] = sd;
        else if (t > j) r[j] *= rinv;
#pragma unroll
        for (int k2 = 0; k2 < 16; k2++) {
          if (k2 > j) {
            float lkj = __shfl(r[j], k2);
            if (t >= k2) r[k2] = fmaf(-r[j], lkj, r[k2]);
          }
        }
      }
#pragma unroll
      for (int k = 0; k < 16; k++) if (k <= t) LB_(p0 + t, p0 + k) = r[k];
      klp += 64.f * logf(r[t]);       // 32*logdetA share
    }
    __syncthreads();
    int NR = 112 - p0;
    if (NR > 0 && tid < NR) {
      int gi = p0 + 16 + tid;
      float a[16];
#pragma unroll
      for (int k = 0; k < 16; k++) a[k] = LB_(gi, p0 + k);
#pragma unroll
      for (int j = 0; j < 16; j++) {
        float inv = 1.f / LB_(p0 + j, p0 + j);
        a[j] *= inv;
#pragma unroll
        for (int k = 0; k < 16; k++)
          if (k > j) a[k] = fmaf(-a[j], LB_(p0 + k, p0 + j), a[k]);
      }
#pragma unroll
      for (int k = 0; k < 16; k++) LB_(gi, p0 + k) = a[k];
    }
    __syncthreads();
    int S = NR;
    if (S > 0) {
      int base = p0 + 16;
      int t4 = S >> 2;
      int ntiles = t4 * t4;
      for (int tt = tid; tt < ntiles; tt += 256) {
        int ti = tt / t4, tj = tt % t4;
        if (ti < tj) continue;
        int gi = base + ti * 4, gj = base + tj * 4;
        float acc[4][4] = {};
#pragma unroll
        for (int j = 0; j < 16; j++) {
          float pa[4], pb[4];
#pragma unroll
          for (int a2 = 0; a2 < 4; a2++) pa[a2] = LB_(gi + a2, p0 + j);
#pragma unroll
          for (int b2 = 0; b2 < 4; b2++) pb[b2] = LB_(gj + b2, p0 + j);
#pragma unroll
          for (int a2 = 0; a2 < 4; a2++)
#pragma unroll
            for (int b2 = 0; b2 < 4; b2++)
              acc[a2][b2] = fmaf(pa[a2], pb[b2], acc[a2][b2]);
        }
#pragma unroll
        for (int a2 = 0; a2 < 4; a2++)
#pragma unroll
          for (int b2 = 0; b2 < 4; b2++)
            LB_(gi + a2, gj + b2) -= acc[a2][b2];
      }
    }
  }
  __syncthreads();

  // ---- Phase 2: invert the 8 diag blocks in place (zero-filled upper)
  {
    float xk[16];
    int cb = tid >> 4, cc = tid & 15;
    if (tid < 128) {
      int g = cb * 16;
#pragma unroll
      for (int rr = 0; rr < 16; rr++) {
        float s = (rr == cc) ? 1.f : 0.f;
#pragma unroll
        for (int k = 0; k < 16; k++)
          if (k < rr) s = fmaf(-LB_(g + rr, g + k), xk[k], s);
        xk[rr] = (rr >= cc) ? s / LB_(g + rr, g + rr) : 0.f;
      }
    }
    __syncthreads();
    if (tid < 128) {
      int g = cb * 16;
#pragma unroll
      for (int rr = 0; rr < 16; rr++) LB_(g + rr, g + cc) = xk[rr];
    }
    __syncthreads();
  }

  // ---- Phase 3: off-diag blocks of X = L^-1
  {
    int r16 = tid >> 4, c16 = tid & 15;
    for (int J = 6; J >= 0; J--) {
      int nb = 7 - J;
      float yv[7];
#pragma unroll
      for (int q = 0; q < 7; q++) {
        if (q < nb) {
          int K = J + 1 + q;
          float s = 0.f;
#pragma unroll
          for (int c2 = 0; c2 < 16; c2++)
            s = fmaf(LB_(K * 16 + r16, J * 16 + c2), LB_(J * 16 + c2, J * 16 + c16), s);
          yv[q] = s;
        }
      }
      __syncthreads();
#pragma unroll
      for (int q = 0; q < 7; q++)
        if (q < nb) LB_((J + 1 + q) * 16 + r16, J * 16 + c16) = yv[q];
      __syncthreads();
      float xv[7];
#pragma unroll
      for (int q = 0; q < 7; q++) {
        if (q < nb) {
          int I = J + 1 + q;
          float s = 0.f;
          for (int K = J + 1; K <= I; K++) {
#pragma unroll
            for (int k = 0; k < 16; k++)
              s = fmaf(LB_(I * 16 + r16, K * 16 + k), LB_(K * 16 + k, J * 16 + c16), s);
          }
          xv[q] = -s;
        }
      }
      __syncthreads();
#pragma unroll
      for (int q = 0; q < 7; q++)
        if (q < nb) LB_((J + 1 + q) * 16 + r16, J * 16 + c16) = xv[q];
      __syncthreads();
    }
  }

  // ---- Phase 4: write Xbf (bf16, zeros above diag); tr(Ainv) = ||X||_F^2
  ushort16* Xb = (ushort16*)(Gbase + (size_t)bh * 65536);
  for (int e = tid; e < MM * MM; e += 256) {
    int r = e >> 7, c = e & 127;
    float xv2 = (c <= r) ? LB_(r, c) : 0.f;
    Xb[e] = f2bf(xv2);
    klp += 32.f * sigma2 * xv2 * xv2;
  }

  // ---- Phase 5: D = X * C fp32, in place over C
  float* Cp = Cws + (size_t)bh * MM * DV;
  {
    float dv[32];
#pragma unroll
    for (int t = 0; t < 32; t++) {
      int e = tid + (t << 8);
      int n = e >> 6, d = e & 63;
      float s = 0.f;
      for (int m = 0; m <= n; m++)
        s = fmaf(LB_(n, m), Cp[(m << 6) + d], s);
      dv[t] = s;
    }
    __syncthreads();
#pragma unroll
    for (int t = 0; t < 32; t++) Cp[tid + (t << 8)] = dv[t];
    __syncthreads();
  }

  // ---- Phase 6: mu_norm2 = ||X^T D||_F^2
  for (int t = 0; t < 32; t++) {
    int e = tid + (t << 8);
    int m = e >> 6, d = e & 63;
    float s = 0.f;
    for (int n = m; n < MM; n++)
      s = fmaf(LB_(n, m), Cp[(n << 6) + d], s);
    klp += 0.5f * s * s;
  }

  // ---- Phase 7: DTbf = bf16(D^T) [d][n]
  ushort16* DTb = (ushort16*)(Gbase + (size_t)bh * 65536 + 32768);
  for (int e = tid; e < DV * MM; e += 256) {
    int d = e >> 7, n = e & 127;
    DTb[e] = f2bf(Cp[n * DV + d]);
  }
  if (tid == 0) klp += -4096.f - 4096.f * ls;   // 0.5*(-k - Dv*M*log(sigma2))
  atomicAdd(&klbuf[bh], klp);
}

// ---------------------------------------------------------------------------
// K4: per (bh, 128-row chunk): proj=q@Om^T (MFMA) -> sincos -> phi(LDS) ->
//     z = phi @ X^T (MFMA, X from global bf16) -> var rowsum+shfl ->
//     mean = z @ DT^T (MFMA) -> sample -> coalesced store via LDS.
// ---------------------------------------------------------------------------
__global__ __launch_bounds__(256)
void k4_sample_mfma(const ushort16* __restrict__ qv, const ushort16* __restrict__ omTbf,
                    const float* __restrict__ phase, const float* __restrict__ log_sf,
                    const float* __restrict__ log_sigma2, const char* __restrict__ Gbase,
                    const float* __restrict__ eps, ushort16* __restrict__ sfeat) {
  __shared__ ushort16 ABuf[128 * 136];   // 34816 B  phi, then z (bf16, [l][·])
  __shared__ ushort16 obuf[128 * 72];    // 18432 B  sample staging
  __shared__ float stdS[128];
  __shared__ float phaseS[MH];
  int blk = blockIdx.x;
  int bh = blk >> 3, l0 = (blk & 7) << 7;
  int h = bh % H_, b = bh / H_;
  int tid = threadIdx.x;
  int wave = tid >> 6, lane = tid & 63;
  int ml = lane & 15, qq = lane >> 4;
  if (tid < MH) phaseS[tid] = phase[h * MH + tid];
  float amp = sqrtf(expf(log_sf[h])) * 0.08838834764831845f;
  float sigma2 = expf(log_sigma2[0]);
  const ushort16* qp = qv + ((size_t)bh * L_ + l0) * MM;
  const ushort16* Om = omTbf + h * MH * DV;
  const ushort16* Xb = (const ushort16*)(Gbase + (size_t)bh * 65536);
  const ushort16* DT = (const ushort16*)(Gbase + (size_t)bh * 65536 + 32768);

  // MFMA1: proj (K=64)
  f32x4 pacc[2][4];
#pragma unroll
  for (int i = 0; i < 2; i++)
#pragma unroll
    for (int j = 0; j < 4; j++) pacc[i][j] = (f32x4){0.f, 0.f, 0.f, 0.f};
#pragma unroll
  for (int k = 0; k < 2; k++) {
    bf16x8 af[2], bfm[4];
#pragma unroll
    for (int i = 0; i < 2; i++)
      af[i] = *(const bf16x8*)&qp[(size_t)(wave * 32 + i * 16 + ml) * MM + k * 32 + qq * 8];
#pragma unroll
    for (int j = 0; j < 4; j++)
      bfm[j] = *(const bf16x8*)&Om[(j * 16 + ml) * DV + k * 32 + qq * 8];
#pragma unroll
    for (int i = 0; i < 2; i++)
#pragma unroll
      for (int j = 0; j < 4; j++)
        pacc[i][j] = __builtin_amdgcn_mfma_f32_16x16x32_bf16(af[i], bfm[j], pacc[i][j], 0, 0, 0);
  }
  __syncthreads();   // phaseS ready
  // sincos -> phi rows (wave-private rows of ABuf)
#pragma unroll
  for (int i = 0; i < 2; i++)
#pragma unroll
    for (int j = 0; j < 4; j++)
#pragma unroll
      for (int e = 0; e < 4; e++) {
        int l = wave * 32 + i * 16 + qq * 4 + e;
        int m = j * 16 + ml;
        float s = pacc[i][j][e] + phaseS[m];
        float sv, cv;
        sincosf(s, &sv, &cv);
        ABuf[l * 136 + m]      = f2bf(amp * cv);
        ABuf[l * 136 + 64 + m] = f2bf(amp * sv);
      }
  // MFMA2: z = phi @ X^T (K=128)
  f32x4 zacc[2][8];
#pragma unroll
  for (int i = 0; i < 2; i++)
#pragma unroll
    for (int j = 0; j < 8; j++) zacc[i][j] = (f32x4){0.f, 0.f, 0.f, 0.f};
#pragma unroll
  for (int k = 0; k < 4; k++) {
    bf16x8 af[2];
#pragma unroll
    for (int i = 0; i < 2; i++)
      af[i] = *(const bf16x8*)&ABuf[(wave * 32 + i * 16 + ml) * 136 + k * 32 + qq * 8];
#pragma unroll
    for (int j = 0; j < 8; j++) {
      bf16x8 bfr = *(const bf16x8*)&Xb[(j * 16 + ml) * MM + k * 32 + qq * 8];
#pragma unroll
      for (int i = 0; i < 2; i++)
        zacc[i][j] = __builtin_amdgcn_mfma_f32_16x16x32_bf16(af[i], bfr, zacc[i][j], 0, 0, 0);
    }
  }
  // var = sigma2 * ||z_row||^2 ; std to LDS
#pragma unroll
  for (int i = 0; i < 2; i++)
#pragma unroll
    for (int e = 0; e < 4; e++) {
      float vs = 0.f;
#pragma unroll
      for (int j = 0; j < 8; j++) vs += zacc[i][j][e] * zacc[i][j][e];
      vs += __shfl_xor(vs, 1);
      vs += __shfl_xor(vs, 2);
      vs += __shfl_xor(vs, 4);
      vs += __shfl_xor(vs, 8);
      if (ml == 0) stdS[wave * 32 + i * 16 + qq * 4 + e] = sqrtf(fmaxf(sigma2 * vs, 0.f));
    }
  // z -> ABuf (overwrite phi; wave-private rows)
#pragma unroll
  for (int i = 0; i < 2; i++)
#pragma unroll
    for (int j = 0; j < 8; j++)
#pragma unroll
      for (int e = 0; e < 4; e++) {
        int l = wave * 32 + i * 16 + qq * 4 + e;
        ABuf[l * 136 + j * 16 + ml] = f2bf(zacc[i][j][e]);
      }
  // MFMA3: mean = z @ DT^T (K=128)
  f32x4 macc[2][4];
#pragma unroll
  for (int i = 0; i < 2; i++)
#pragma unroll
    for (int j = 0; j < 4; j++) macc[i][j] = (f32x4){0.f, 0.f, 0.f, 0.f};
#pragma unroll
  for (int k = 0; k < 4; k++) {
    bf16x8 af[2];
#pragma unroll
    for (int i = 0; i < 2; i++)
      af[i] = *(const bf16x8*)&ABuf[(wave * 32 + i * 16 + ml) * 136 + k * 32 + qq * 8];
#pragma unroll
    for (int j = 0; j < 4; j++) {
      bf16x8 bfr = *(const bf16x8*)&DT[(j * 16 + ml) * MM + k * 32 + qq * 8];
#pragma unroll
      for (int i = 0; i < 2; i++)
        macc[i][j] = __builtin_amdgcn_mfma_f32_16x16x32_bf16(af[i], bfr, macc[i][j], 0, 0, 0);
    }
  }
  // sample + stage
  const float* ep = eps + ((size_t)bh * L_ + l0) * DV;
#pragma unroll
  for (int i = 0; i < 2; i++)
#pragma unroll
    for (int j = 0; j < 4; j++)
#pragma unroll
      for (int e = 0; e < 4; e++) {
        int l = wave * 32 + i * 16 + qq * 4 + e;
        int d = j * 16 + ml;
        float smp = macc[i][j][e] + stdS[l] * ep[l * DV + d];
        obuf[l * 72 + d] = f2bf(smp);
      }
  __syncthreads();
  // coalesced store: row = 64 bf16 = 4 uint4
  ushort16* sp = sfeat + ((size_t)b * L_ + l0) * HD + h * DV;
  for (int u = tid; u < 512; u += 256) {
    int row = u >> 2, part = u & 3;
    uint4 val = *(const uint4*)&obuf[row * 72 + part * 8];
    *(uint4*)&sp[(size_t)row * HD + part * 8] = val;
  }
}

// ---------------------------------------------------------------------------
// K5: out = sfeat @ Wo^T + b, bf16 MFMA (Wo converted during staging), fp32 out
// ---------------------------------------------------------------------------
__global__ __launch_bounds__(256)
void k5_out_mfma(const ushort16* __restrict__ sfeat, const float* __restrict__ Wo,
                 const float* __restrict__ bias, float* __restrict__ outp) {
  __shared__ ushort16 As[128 * 40];
  __shared__ ushort16 Bs[128 * 40];
  int tid = threadIdx.x;
  int tn = blockIdx.x % 6;
  int tm = blockIdx.x / 6;
  int m0 = tm * 128, n0 = tn * 128;
  int wave = tid >> 6, lane = tid & 63;
  int wy = wave >> 1, wx = wave & 1;
  int mlane = lane & 15, q = lane >> 4;
  f32x4 acc[4][4];
#pragma unroll
  for (int i = 0; i < 4; i++)
#pragma unroll
    for (int j = 0; j < 4; j++) acc[i][j] = (f32x4){0.f, 0.f, 0.f, 0.f};

  int c0 = tid, c1 = tid + 256;
  int rowA0 = c0 >> 2, ka0 = (c0 & 3) * 8;
  int rowA1 = c1 >> 2, ka1 = (c1 & 3) * 8;

  for (int k0 = 0; k0 < HD; k0 += 32) {
    __syncthreads();
    uint4 a0 = *(const uint4*)&sfeat[(size_t)(m0 + rowA0) * HD + k0 + ka0];
    uint4 a1 = *(const uint4*)&sfeat[(size_t)(m0 + rowA1) * HD + k0 + ka1];
    float4 w00 = *(const float4*)&Wo[(size_t)(n0 + rowA0) * HD + k0 + ka0];
    float4 w01 = *(const float4*)&Wo[(size_t)(n0 + rowA0) * HD + k0 + ka0 + 4];
    float4 w10 = *(const float4*)&Wo[(size_t)(n0 + rowA1) * HD + k0 + ka1];
    float4 w11 = *(const float4*)&Wo[(size_t)(n0 + rowA1) * HD + k0 + ka1 + 4];
    uint4 b0, b1;
    b0.x = pack2bf(w00.x, w00.y); b0.y = pack2bf(w00.z, w00.w);
    b0.z = pack2bf(w01.x, w01.y); b0.w = pack2bf(w01.z, w01.w);
    b1.x = pack2bf(w10.x, w10.y); b1.y = pack2bf(w10.z, w10.w);
    b1.z = pack2bf(w11.x, w11.y); b1.w = pack2bf(w11.z, w11.w);
    *(uint4*)&As[rowA0 * 40 + ka0] = a0;
    *(uint4*)&As[rowA1 * 40 + ka1] = a1;
    *(uint4*)&Bs[rowA0 * 40 + ka0] = b0;
    *(uint4*)&Bs[rowA1 * 40 + ka1] = b1;
    __syncthreads();
    bf16x8 av[4], bv[4];
#pragma unroll
    for (int i = 0; i < 4; i++)
      av[i] = *(const bf16x8*)&As[(wy * 64 + i * 16 + mlane) * 40 + q * 8];
#pragma unroll
    for (int j = 0; j < 4; j++)
      bv[j] = *(const bf16x8*)&Bs[(wx * 64 + j * 16 + mlane) * 40 + q * 8];
#pragma unroll
    for (int i = 0; i < 4; i++)
#pragma unroll
      for (int j = 0; j < 4; j++)
        acc[i][j] = __builtin_amdgcn_mfma_f32_16x16x32_bf16(av[i], bv[j], acc[i][j], 0, 0, 0);
  }
  float bsv[4];
#pragma unroll
  for (int j = 0; j < 4; j++) bsv[j] = bias[n0 + wx * 64 + j * 16 + mlane];
#pragma unroll
  for (int i = 0; i < 4; i++) {
#pragma unroll
    for (int e = 0; e < 4; e++) {
      int gm = m0 + wy * 64 + i * 16 + q * 4 + e;
#pragma unroll
      for (int j = 0; j < 4; j++) {
        int gn = n0 + wx * 64 + j * 16 + mlane;
        outp[(size_t)gm * HD + gn] = acc[i][j][e] + bsv[j];
      }
    }
  }
}

// ---------------------------------------------------------------------------
// K6: kl = sum(klbuf)/B  -> out[25165824]
// ---------------------------------------------------------------------------
__global__ void k6_kl(const float* __restrict__ klbuf, float* __restrict__ outp) {
  __shared__ float red[2];
  int tid = threadIdx.x;   // 128
  float s = 0.f;
  for (int e = tid; e < BH_; e += 128) s += klbuf[e];
  for (int off = 32; off >= 1; off >>= 1) s += __shfl_xor(s, off);
  if ((tid & 63) == 0) red[tid >> 6] = s;
  __syncthreads();
  if (tid == 0) outp[(size_t)B_ * L_ * HD] = (red[0] + red[1]) * (1.f / 32.f);
}

// ---------------------------------------------------------------------------
extern "C" void kernel_launch(void* const* d_in, const int* in_sizes, int n_in,
                              void* d_out, int out_size, void* d_ws, size_t ws_size,
                              hipStream_t stream) {
  (void)in_sizes; (void)n_in; (void)out_size; (void)ws_size;
  const float* x       = (const float*)d_in[0];
  const float* Wqv     = (const float*)d_in[1];
  const float* log_sf  = (const float*)d_in[2];
  const float* log_ls  = (const float*)d_in[3];
  const float* log_s2  = (const float*)d_in[4];
  const float* omega_h = (const float*)d_in[5];
  const float* phase   = (const float*)d_in[6];
  const float* Wo      = (const float*)d_in[7];
  const float* Wob     = (const float*)d_in[8];
  const float* eps     = (const float*)d_in[9];
  float* outp = (float*)d_out;

  // Workspace layout (total 188,941,824 bytes):
  char* ws = (char*)d_ws;
  ushort16* qv    = (ushort16*)(ws);                    // bf16 [b][h][l][128]  100,663,296 B
  ushort16* xbf   = (ushort16*)(ws + 100663296);        // bf16 x; later sfeat   50,331,648 B
  ushort16* sfeat = xbf;                                // alias (k1 done with xbf before k4)
  ushort16* omTbf = (ushort16*)(ws + 150994944);        // bf16 [h][m][d]            98,304 B
  char*     Gbase = ws + 151191552;                     // 384 x 65536 B slots:
                                                        //  G fp32 -> Xbf+DTbf bf16
  ushort16* wqvbf = (ushort16*)(ws + 151191552);        // bf16 Wqv (pre-k2 only) 2,359,296 B
  float*    Cws   = (float*)(ws + 176357376);           // C -> D fp32           12,582,912 B
  float*    klbuf = (float*)(ws + 188940288);           // per-(b,h) KL               1,536 B

  hipLaunchKernelGGL(k0_prep,       dim3(1024), dim3(256), 0, stream, x, Wqv, omega_h, log_ls, xbf, wqvbf, omTbf, klbuf);
  hipLaunchKernelGGL(k1_qv_mfma,    dim3(3072), dim3(256), 0, stream, xbf, wqvbf, qv);
  hipLaunchKernelGGL(k2_gram_mfma,  dim3(BH_),  dim3(256), 0, stream, qv, omTbf, phase, log_sf, Gbase, Cws);
  hipLaunchKernelGGL(k3_factor,     dim3(BH_),  dim3(256), 0, stream, Gbase, Cws, log_s2, klbuf);
  hipLaunchKernelGGL(k4_sample_mfma,dim3(3072), dim3(256), 0, stream, qv, omTbf, phase, log_sf, log_s2, Gbase, eps, sfeat);
  hipLaunchKernelGGL(k5_out_mfma,   dim3(1536), dim3(256), 0, stream, sfeat, Wo, Wob, outp);
  hipLaunchKernelGGL(k6_kl,         dim3(1),    dim3(128), 0, stream, klbuf, outp);
}